// Round 5
// baseline (223.735 us; speedup 1.0000x reference)
//
#include <hip/hip_runtime.h>

typedef __attribute__((ext_vector_type(8))) short short8;
typedef __attribute__((ext_vector_type(4))) float f32x4;

#define AS3P(x) ((__attribute__((address_space(3))) void*)(x))
#define AS1P(x) ((const __attribute__((address_space(1))) void*)(x))

__device__ __forceinline__ unsigned short f2bf(float f) {
    unsigned int u = __float_as_uint(f);
    u += 0x7fffu + ((u >> 16) & 1u);   // RNE
    return (unsigned short)(u >> 16);
}
__device__ __forceinline__ float bf2f(unsigned short b) {
    return __uint_as_float(((unsigned int)b) << 16);
}
__device__ __forceinline__ unsigned int pk2bf(float a, float b) {
    return (unsigned int)f2bf(a) | ((unsigned int)f2bf(b) << 16);
}
__device__ __forceinline__ float waveReduceSum(float v) {
    #pragma unroll
    for (int off = 32; off; off >>= 1) v += __shfl_xor(v, off, 64);
    return v;
}

// ---------------- prep: enc_w cast (bx<512) | items norm + cates + items_bf (bx>=512) ----------------
__global__ __launch_bounds__(256) void k_prep(const float* __restrict__ enc_w,
                                              unsigned short* __restrict__ encw,
                                              const float* __restrict__ item_emb,
                                              const float* __restrict__ proto,
                                              unsigned short* __restrict__ items_bf,
                                              float* __restrict__ catesT) {
    __shared__ float sp[256];
    int bx = blockIdx.x, tid = threadIdx.x;
    if (bx < 512) {
        size_t i = ((size_t)bx * 256 + tid) * 8;
        float4 a = *(const float4*)(enc_w + i);
        float4 b = *(const float4*)(enc_w + i + 4);
        uint4 pk;
        pk.x = pk2bf(a.x, a.y); pk.y = pk2bf(a.z, a.w);
        pk.z = pk2bf(b.x, b.y); pk.w = pk2bf(b.z, b.w);
        *(uint4*)(encw + i) = pk;
        return;
    }
    sp[tid] = proto[tid];
    __syncthreads();
    {
        float v = sp[tid];
        float ss = waveReduceSum(v * v);   // wave w == proto row w
        sp[tid] = v * (1.f / fmaxf(sqrtf(ss), 1e-12f));
    }
    __syncthreads();
    int i = (bx - 512) * 256 + tid;
    const float4* row = (const float4*)(item_emb + (size_t)i * 64);
    float4 f[16];
    float ss = 0.f;
    #pragma unroll
    for (int q = 0; q < 16; ++q) {
        f[q] = row[q];
        ss += f[q].x * f[q].x + f[q].y * f[q].y + f[q].z * f[q].z + f[q].w * f[q].w;
    }
    float inv = 1.f / fmaxf(sqrtf(ss), 1e-12f);
    float dots[4] = {0.f, 0.f, 0.f, 0.f};
    unsigned short* ob = items_bf + (size_t)i * 64;
    #pragma unroll
    for (int q = 0; q < 16; ++q) {
        f[q].x *= inv; f[q].y *= inv; f[q].z *= inv; f[q].w *= inv;
        #pragma unroll
        for (int k = 0; k < 4; ++k) {
            dots[k] += f[q].x * sp[k * 64 + q * 4 + 0] + f[q].y * sp[k * 64 + q * 4 + 1]
                     + f[q].z * sp[k * 64 + q * 4 + 2] + f[q].w * sp[k * 64 + q * 4 + 3];
        }
    }
    #pragma unroll
    for (int q = 0; q < 16; q += 2) {
        uint4 pk;
        pk.x = pk2bf(f[q].x, f[q].y);         pk.y = pk2bf(f[q].z, f[q].w);
        pk.z = pk2bf(f[q + 1].x, f[q + 1].y); pk.w = pk2bf(f[q + 1].z, f[q + 1].w);
        *(uint4*)(ob + q * 4) = pk;
    }
    float m = fmaxf(fmaxf(dots[0], dots[1]), fmaxf(dots[2], dots[3]));
    float e0 = expf(dots[0] - m), e1 = expf(dots[1] - m), e2 = expf(dots[2] - m), e3 = expf(dots[3] - m);
    float is = 1.f / (e0 + e1 + e2 + e3);
    catesT[0 * 8192 + i] = e0 * is;
    catesT[1 * 8192 + i] = e1 * is;
    catesT[2 * 8192 + i] = e2 * is;
    catesT[3 * 8192 + i] = e3 * is;
}

// ---------------- adj GEMM: A = f32 adj via global_load_lds, cvt after ds_read ----------------
// partials[z][8192][128] (bf16) = adj[8192 x Kslice] * B^T ; B bf16 [128][8192]
__global__ __launch_bounds__(256) void k_gemm_f32A(const float* __restrict__ A,
                                                   const unsigned short* __restrict__ B,
                                                   unsigned short* __restrict__ Cout,
                                                   int ksplit) {
    __shared__ float lAf[128 * 64];            // 32 KiB, rows of 256B, 16B-granule XOR swizzle
    __shared__ unsigned short lB[128 * 64];    // 16 KiB
    int tid = threadIdx.x;
    int lane = tid & 63;
    int w = tid >> 6;
    int wr = w >> 1, wc = w & 1;
    int mBase = blockIdx.y * 128;
    int Kbeg = blockIdx.z * ksplit;
    int Kend = Kbeg + ksplit;

    f32x4 acc[4][4] = {};

    const float* Ablk = A + (size_t)mBase * 8192;
    // A staging geometry: iter it covers rows it*16..it*16+15 (16 rows x 256B = 4KB)
    int arow_l = w * 4 + (lane >> 4);          // row low 4 bits (0..15)
    int aq = lane & 15;                        // physical 16B slot within row
    int acol = (aq ^ arow_l) * 4;              // swizzled source float col
    // B staging (r4-proven pattern)
    int srow = tid >> 3;
    int scg = (tid & 7) ^ (srow & 7);
    char* ldsA_w = (char*)lAf + w * 1024;
    char* ldsB_w = (char*)lB + w * 1024;

    for (int k0 = Kbeg; k0 < Kend; k0 += 64) {
        __syncthreads();
        #pragma unroll
        for (int it = 0; it < 8; ++it) {
            int row = it * 16 + arow_l;
            const float* ga = Ablk + (size_t)row * 8192 + k0 + acol;
            __builtin_amdgcn_global_load_lds(AS1P(ga), AS3P(ldsA_w + it * 4096), 16, 0, 0);
        }
        #pragma unroll
        for (int it = 0; it < 4; ++it) {
            const unsigned short* gb = B + (size_t)(it * 32 + srow) * 8192 + k0 + scg * 8;
            __builtin_amdgcn_global_load_lds(AS1P(gb), AS3P(ldsB_w + it * 4096), 16, 0, 0);
        }
        __syncthreads();
        #pragma unroll
        for (int kk = 0; kk < 2; ++kk) {
            short8 af[4], bfr[4];
            #pragma unroll
            for (int i = 0; i < 4; ++i) {
                int rowa = wr * 64 + i * 16 + (lane & 15);
                int slot = kk * 4 + (lane >> 4);
                const char* pbase = (const char*)lAf + rowa * 256;
                int q0 = (2 * slot) ^ (rowa & 15);
                float4 fa = *(const float4*)(pbase + q0 * 16);
                float4 fb = *(const float4*)(pbase + (q0 ^ 1) * 16);
                union { unsigned int u[4]; short8 s; } cv;
                cv.u[0] = pk2bf(fa.x, fa.y); cv.u[1] = pk2bf(fa.z, fa.w);
                cv.u[2] = pk2bf(fb.x, fb.y); cv.u[3] = pk2bf(fb.z, fb.w);
                af[i] = cv.s;
                int rowb = wc * 64 + i * 16 + (lane & 15);
                bfr[i] = *(const short8*)((const char*)lB + rowb * 128 + ((slot ^ (rowb & 7)) * 16));
            }
            #pragma unroll
            for (int i = 0; i < 4; ++i)
                #pragma unroll
                for (int j = 0; j < 4; ++j)
                    acc[i][j] = __builtin_amdgcn_mfma_f32_16x16x32_bf16(af[i], bfr[j], acc[i][j], 0, 0, 0);
        }
    }

    unsigned short* outP = Cout + (size_t)blockIdx.z * 8192 * 128;
    #pragma unroll
    for (int i = 0; i < 4; ++i) {
        int rbase = mBase + wr * 64 + i * 16 + (lane >> 4) * 4;
        #pragma unroll
        for (int j = 0; j < 4; ++j) {
            int col = wc * 64 + j * 16 + (lane & 15);
            #pragma unroll
            for (int r = 0; r < 4; ++r)
                outP[(size_t)(rbase + r) * 128 + col] = f2bf(acc[i][j][r]);
        }
    }
}

// ---------------- MFMA GEMM (bf16 A/B via global_load_lds), bf16 split-K partials ----------------
__global__ __launch_bounds__(256) void k_gemm_part(const unsigned short* __restrict__ A,
                                                   const unsigned short* __restrict__ B,
                                                   unsigned short* __restrict__ Cout,
                                                   int M, int ksplit, int lda, int ldb, int ldc) {
    __shared__ unsigned short lA[128 * 64];
    __shared__ unsigned short lB[128 * 64];
    int tid = threadIdx.x;
    int lane = tid & 63;
    int w = tid >> 6;
    int wr = w >> 1, wc = w & 1;
    int mBase = blockIdx.y * 128;
    int nBase = blockIdx.x * 128;
    int Kbeg = blockIdx.z * ksplit;
    int Kend = Kbeg + ksplit;

    f32x4 acc[4][4] = {};

    const unsigned short* Ablk = A + (size_t)mBase * lda;
    const unsigned short* Bblk = B + (size_t)nBase * ldb;
    int srow = tid >> 3;
    int scg = (tid & 7) ^ (srow & 7);
    char* ldsA_w = (char*)lA + w * 1024;
    char* ldsB_w = (char*)lB + w * 1024;

    for (int k0 = Kbeg; k0 < Kend; k0 += 64) {
        __syncthreads();
        #pragma unroll
        for (int it = 0; it < 4; ++it) {
            const unsigned short* ga = Ablk + (size_t)(it * 32 + srow) * lda + k0 + scg * 8;
            __builtin_amdgcn_global_load_lds(AS1P(ga), AS3P(ldsA_w + it * 4096), 16, 0, 0);
            const unsigned short* gb = Bblk + (size_t)(it * 32 + srow) * ldb + k0 + scg * 8;
            __builtin_amdgcn_global_load_lds(AS1P(gb), AS3P(ldsB_w + it * 4096), 16, 0, 0);
        }
        __syncthreads();
        #pragma unroll
        for (int kk = 0; kk < 2; ++kk) {
            short8 af[4], bfr[4];
            #pragma unroll
            for (int i = 0; i < 4; ++i) {
                int rowa = wr * 64 + i * 16 + (lane & 15);
                int slot = kk * 4 + (lane >> 4);
                af[i] = *(const short8*)((const char*)lA + rowa * 128 + ((slot ^ (rowa & 7)) * 16));
                int rowb = wc * 64 + i * 16 + (lane & 15);
                bfr[i] = *(const short8*)((const char*)lB + rowb * 128 + ((slot ^ (rowb & 7)) * 16));
            }
            #pragma unroll
            for (int i = 0; i < 4; ++i)
                #pragma unroll
                for (int j = 0; j < 4; ++j)
                    acc[i][j] = __builtin_amdgcn_mfma_f32_16x16x32_bf16(af[i], bfr[j], acc[i][j], 0, 0, 0);
        }
    }

    unsigned short* outP = Cout + (size_t)blockIdx.z * M * ldc;
    #pragma unroll
    for (int i = 0; i < 4; ++i) {
        int rbase = mBase + wr * 64 + i * 16 + (lane >> 4) * 4;
        #pragma unroll
        for (int j = 0; j < 4; ++j) {
            int col = nBase + wc * 64 + j * 16 + (lane & 15);
            #pragma unroll
            for (int r = 0; r < 4; ++r)
                outP[(size_t)(rbase + r) * ldc + col] = f2bf(acc[i][j][r]);
        }
    }
}

// bx<128: sum 16 bf16 partials, transpose -> W1T[o][n]   |   bx>=128: rating cast + inv4
__global__ __launch_bounds__(256) void k_red1(const unsigned short* __restrict__ part,
                                              unsigned short* __restrict__ outT,
                                              const float* __restrict__ rating,
                                              const float* __restrict__ catesT,
                                              unsigned short* __restrict__ rating_bf,
                                              float* __restrict__ inv4) {
    __shared__ float t[64 * 129];
    int tid = threadIdx.x;
    if (blockIdx.x < 128) {
        int m0 = blockIdx.x * 64;
        #pragma unroll
        for (int j = 0; j < 4; ++j) {
            int f = tid + j * 256;
            int m = f >> 4, o = (f & 15) * 8;
            float a[8] = {0.f,0.f,0.f,0.f,0.f,0.f,0.f,0.f};
            #pragma unroll
            for (int sp = 0; sp < 16; ++sp) {
                const unsigned short* p = part + (size_t)sp * 8192 * 128 + (size_t)(m0 + m) * 128 + o;
                uint4 v = *(const uint4*)p;
                a[0] += bf2f((unsigned short)(v.x & 0xffff)); a[1] += bf2f((unsigned short)(v.x >> 16));
                a[2] += bf2f((unsigned short)(v.y & 0xffff)); a[3] += bf2f((unsigned short)(v.y >> 16));
                a[4] += bf2f((unsigned short)(v.z & 0xffff)); a[5] += bf2f((unsigned short)(v.z >> 16));
                a[6] += bf2f((unsigned short)(v.w & 0xffff)); a[7] += bf2f((unsigned short)(v.w >> 16));
            }
            #pragma unroll
            for (int e = 0; e < 8; ++e) t[m * 129 + o + e] = a[e];
        }
        __syncthreads();
        #pragma unroll
        for (int j = 0; j < 16; ++j) {
            int idx = tid + j * 256;
            int o = idx >> 5, mp = idx & 31;
            float v0 = t[(mp * 2 + 0) * 129 + o];
            float v1 = t[(mp * 2 + 1) * 129 + o];
            *(unsigned int*)(outT + (size_t)o * 8192 + m0 + mp * 2) = pk2bf(v0, v1);
        }
        return;
    }
    int b = blockIdx.x - 128;
    const float* row = rating + (size_t)b * 8192;
    float s0 = 0.f, s1 = 0.f, s2 = 0.f, s3 = 0.f;
    #pragma unroll
    for (int j = 0; j < 8; ++j) {
        int i4 = tid + j * 256;
        float4 r = *(const float4*)(row + i4 * 4);
        ushort4 pk;
        pk.x = f2bf(r.x); pk.y = f2bf(r.y); pk.z = f2bf(r.z); pk.w = f2bf(r.w);
        *(ushort4*)(rating_bf + (size_t)b * 8192 + i4 * 4) = pk;
        float4 c0 = *(const float4*)(catesT + 0 * 8192 + i4 * 4);
        float4 c1 = *(const float4*)(catesT + 1 * 8192 + i4 * 4);
        float4 c2 = *(const float4*)(catesT + 2 * 8192 + i4 * 4);
        float4 c3 = *(const float4*)(catesT + 3 * 8192 + i4 * 4);
        float px, py, pz, pw;
        px = r.x * c0.x; py = r.y * c0.y; pz = r.z * c0.z; pw = r.w * c0.w;
        s0 += px * px + py * py + pz * pz + pw * pw;
        px = r.x * c1.x; py = r.y * c1.y; pz = r.z * c1.z; pw = r.w * c1.w;
        s1 += px * px + py * py + pz * pz + pw * pw;
        px = r.x * c2.x; py = r.y * c2.y; pz = r.z * c2.z; pw = r.w * c2.w;
        s2 += px * px + py * py + pz * pz + pw * pw;
        px = r.x * c3.x; py = r.y * c3.y; pz = r.z * c3.z; pw = r.w * c3.w;
        s3 += px * px + py * py + pz * pz + pw * pw;
    }
    s0 = waveReduceSum(s0); s1 = waveReduceSum(s1);
    s2 = waveReduceSum(s2); s3 = waveReduceSum(s3);
    if ((tid & 63) == 0) {
        int w = tid >> 6;
        t[w * 4 + 0] = s0; t[w * 4 + 1] = s1; t[w * 4 + 2] = s2; t[w * 4 + 3] = s3;
    }
    __syncthreads();
    if (tid < 4) {
        float ss = t[0 * 4 + tid] + t[1 * 4 + tid] + t[2 * 4 + tid] + t[3 * 4 + tid];
        inv4[b * 4 + tid] = 1.f / fmaxf(sqrtf(ss), 1e-12f);
    }
}

// sum 16 partials; epilogue builds G[k*128+o][n] = bf16(cates[k][n] * 0.5*(W2[n][o]+enc_w[o][n]))
__global__ __launch_bounds__(256) void k_reduce_TG(const unsigned short* __restrict__ part,
                                                   const float* __restrict__ enc_w,
                                                   const float* __restrict__ catesT,
                                                   unsigned short* __restrict__ G) {
    __shared__ float t[64 * 129];
    int m0 = blockIdx.x * 64;
    int tid = threadIdx.x;
    #pragma unroll
    for (int j = 0; j < 4; ++j) {
        int f = tid + j * 256;
        int m = f >> 4, o = (f & 15) * 8;
        float a[8] = {0.f,0.f,0.f,0.f,0.f,0.f,0.f,0.f};
        #pragma unroll
        for (int sp = 0; sp < 16; ++sp) {
            const unsigned short* p = part + (size_t)sp * 8192 * 128 + (size_t)(m0 + m) * 128 + o;
            uint4 v = *(const uint4*)p;
            a[0] += bf2f((unsigned short)(v.x & 0xffff)); a[1] += bf2f((unsigned short)(v.x >> 16));
            a[2] += bf2f((unsigned short)(v.y & 0xffff)); a[3] += bf2f((unsigned short)(v.y >> 16));
            a[4] += bf2f((unsigned short)(v.z & 0xffff)); a[5] += bf2f((unsigned short)(v.z >> 16));
            a[6] += bf2f((unsigned short)(v.w & 0xffff)); a[7] += bf2f((unsigned short)(v.w >> 16));
        }
        #pragma unroll
        for (int e = 0; e < 8; ++e) t[m * 129 + o + e] = a[e];
    }
    __syncthreads();
    #pragma unroll
    for (int j = 0; j < 16; ++j) {
        int idx = tid + j * 256;
        int o = idx >> 5, mp = idx & 31;
        int m = m0 + mp * 2;
        float v0 = t[(mp * 2 + 0) * 129 + o];
        float v1 = t[(mp * 2 + 1) * 129 + o];
        v0 = 0.5f * (v0 + enc_w[(size_t)o * 8192 + m + 0]);
        v1 = 0.5f * (v1 + enc_w[(size_t)o * 8192 + m + 1]);
        #pragma unroll
        for (int k = 0; k < 4; ++k) {
            float c0 = catesT[(size_t)k * 8192 + m + 0];
            float c1 = catesT[(size_t)k * 8192 + m + 1];
            *(unsigned int*)(G + (size_t)(k * 128 + o) * 8192 + m) = pk2bf(v0 * c0, v1 * c1);
        }
    }
}

// sum 16 bf16 h-partials, scale by inv4, +bias; write mu (f32 + bf16) and logvar
__global__ __launch_bounds__(128) void k_reduce_h2(const unsigned short* __restrict__ hpart,
                                                   const float* __restrict__ enc_b,
                                                   const float* __restrict__ inv4,
                                                   unsigned short* __restrict__ mu_bf,
                                                   float* __restrict__ outp) {
    int r = blockIdx.x;                 // k*512 + b
    int k = r >> 9, b = r & 511;
    int o = threadIdx.x;
    float s = 0.f;
    #pragma unroll
    for (int sp = 0; sp < 16; ++sp)
        s += bf2f(hpart[(size_t)sp * 262144 + (size_t)b * 512 + k * 128 + o]);
    s = s * inv4[b * 4 + k] + enc_b[o];
    const size_t MU0 = (size_t)512 * 8192;
    const size_t LV0 = MU0 + (size_t)2048 * 64;
    if (o < 64) {
        float ss = s * s;
        #pragma unroll
        for (int off = 32; off; off >>= 1) ss += __shfl_xor(ss, off, 64);
        float inv = 1.f / fmaxf(sqrtf(ss), 1e-12f);
        float mv = s * inv;
        outp[MU0 + (size_t)r * 64 + o] = mv;
        mu_bf[(size_t)r * 64 + o] = f2bf(mv);
    } else {
        outp[LV0 + (size_t)r * 64 + (o - 64)] = -s;
    }
}

// MFMA logits: per block 128(b) x 128(n), loop 4 protos; out = log(sum_k exp(z_k . item) * cates_k)
__global__ __launch_bounds__(256) void k_logits_mfma(const unsigned short* __restrict__ mu_bf,
                                                     const unsigned short* __restrict__ items_bf,
                                                     const float* __restrict__ catesT,
                                                     float* __restrict__ out) {
    __shared__ unsigned short lA[128 * 64];
    __shared__ unsigned short lB[128 * 64];
    int tid = threadIdx.x;
    int lane = tid & 63, w = tid >> 6, wr = w >> 1, wc = w & 1;
    int nBase = blockIdx.x * 128, bBase = blockIdx.y * 128;
    int srow = tid >> 3;
    int scg = (tid & 7) ^ (srow & 7);
    char* ldsA_w = (char*)lA + w * 1024;
    char* ldsB_w = (char*)lB + w * 1024;

    #pragma unroll
    for (int it = 0; it < 4; ++it) {
        const unsigned short* gb = items_bf + (size_t)(nBase + it * 32 + srow) * 64 + scg * 8;
        __builtin_amdgcn_global_load_lds(AS1P(gb), AS3P(ldsB_w + it * 4096), 16, 0, 0);
    }

    f32x4 p[4][4] = {};
    for (int k = 0; k < 4; ++k) {
        __syncthreads();
        #pragma unroll
        for (int it = 0; it < 4; ++it) {
            const unsigned short* ga = mu_bf + (size_t)(k * 512 + bBase + it * 32 + srow) * 64 + scg * 8;
            __builtin_amdgcn_global_load_lds(AS1P(ga), AS3P(ldsA_w + it * 4096), 16, 0, 0);
        }
        __syncthreads();
        f32x4 acc[4][4] = {};
        #pragma unroll
        for (int kk = 0; kk < 2; ++kk) {
            short8 af[4], bfr[4];
            #pragma unroll
            for (int i = 0; i < 4; ++i) {
                int rowa = wr * 64 + i * 16 + (lane & 15);
                int slot = kk * 4 + (lane >> 4);
                af[i] = *(const short8*)((const char*)lA + rowa * 128 + ((slot ^ (rowa & 7)) * 16));
                int rowb = wc * 64 + i * 16 + (lane & 15);
                bfr[i] = *(const short8*)((const char*)lB + rowb * 128 + ((slot ^ (rowb & 7)) * 16));
            }
            #pragma unroll
            for (int i = 0; i < 4; ++i)
                #pragma unroll
                for (int j = 0; j < 4; ++j)
                    acc[i][j] = __builtin_amdgcn_mfma_f32_16x16x32_bf16(af[i], bfr[j], acc[i][j], 0, 0, 0);
        }
        #pragma unroll
        for (int j = 0; j < 4; ++j) {
            int col = nBase + wc * 64 + j * 16 + (lane & 15);
            float c = catesT[(size_t)k * 8192 + col];
            #pragma unroll
            for (int i = 0; i < 4; ++i)
                #pragma unroll
                for (int r = 0; r < 4; ++r)
                    p[i][j][r] += __expf(acc[i][j][r]) * c;
        }
    }
    #pragma unroll
    for (int i = 0; i < 4; ++i) {
        int rbase = bBase + wr * 64 + i * 16 + (lane >> 4) * 4;
        #pragma unroll
        for (int j = 0; j < 4; ++j) {
            int col = nBase + wc * 64 + j * 16 + (lane & 15);
            #pragma unroll
            for (int r = 0; r < 4; ++r)
                out[(size_t)(rbase + r) * 8192 + col] = __logf(p[i][j][r]);
        }
    }
}

extern "C" void kernel_launch(void* const* d_in, const int* in_sizes, int n_in,
                              void* d_out, int out_size, void* d_ws, size_t ws_size,
                              hipStream_t stream) {
    const float* rating   = (const float*)d_in[0];   // [512][8192]
    const float* adj      = (const float*)d_in[1];   // [8192][8192]
    const float* item_emb = (const float*)d_in[2];   // [8192][64]
    const float* proto    = (const float*)d_in[3];   // [4][64]
    const float* enc_w    = (const float*)d_in[4];   // [128][8192]
    const float* enc_b    = (const float*)d_in[5];   // [128]
    float* out = (float*)d_out;

    char* ws = (char*)d_ws;
    unsigned short* part_bf   = (unsigned short*)ws;                      // 16*8192*128 bf16 = 32 MiB
    unsigned short* rating_bf = part_bf + (size_t)16 * 8192 * 128;        // 8 MiB
    unsigned short* G         = rating_bf + (size_t)512 * 8192;           // 8 MiB
    unsigned short* W1T       = G + (size_t)512 * 8192;                   // 2 MiB
    unsigned short* encw      = W1T + (size_t)128 * 8192;                 // 2 MiB
    unsigned short* hpart     = encw + (size_t)128 * 8192;                // 16*512*512 bf16 = 8 MiB
    unsigned short* items_bf  = hpart + (size_t)16 * 512 * 512;           // 1 MiB
    unsigned short* mu_bf     = items_bf + (size_t)8192 * 64;             // 0.25 MiB
    float* catesT = (float*)(mu_bf + (size_t)2048 * 64);                  // 4*8192 f32
    float* inv4   = catesT + (size_t)4 * 8192;                            // 2048 f32

    // prep: enc_w->bf16 (512 blk) | items norm + cates (32 blk)
    k_prep<<<544, 256, 0, stream>>>(enc_w, encw, item_emb, proto, items_bf, catesT);

    // W1 = adj @ enc_w^T  (f32 adj, split-K 16)
    k_gemm_f32A<<<dim3(1, 64, 16), 256, 0, stream>>>(adj, encw, part_bf, 512);
    // reduce->W1T (128 blk) | rating cast + inv4 (512 blk)
    k_red1<<<640, 256, 0, stream>>>(part_bf, W1T, rating, catesT, rating_bf, inv4);

    // W2 = adj @ W1 ; epilogue builds G = cates * W3
    k_gemm_f32A<<<dim3(1, 64, 16), 256, 0, stream>>>(adj, W1T, part_bf, 512);
    k_reduce_TG<<<128, 256, 0, stream>>>(part_bf, enc_w, catesT, G);

    // h = rating_bf @ G^T  (split-K 16)
    k_gemm_part<<<dim3(4, 4, 16), 256, 0, stream>>>(rating_bf, G, hpart, 512, 512, 8192, 8192, 512);
    k_reduce_h2<<<2048, 128, 0, stream>>>(hpart, enc_b, inv4, mu_bf, out);

    k_logits_mfma<<<dim3(64, 4), 256, 0, stream>>>(mu_bf, items_bf, catesT, out);
}

// Round 6
// 199.336 us; speedup vs baseline: 1.1224x; 1.1224x over previous
//
#include <hip/hip_runtime.h>

typedef __attribute__((ext_vector_type(8))) short short8;
typedef __attribute__((ext_vector_type(4))) float f32x4;

#define AS3P(x) ((__attribute__((address_space(3))) void*)(x))
#define AS1P(x) ((const __attribute__((address_space(1))) void*)(x))

__device__ __forceinline__ unsigned short f2bf(float f) {
    unsigned int u = __float_as_uint(f);
    u += 0x7fffu + ((u >> 16) & 1u);   // RNE
    return (unsigned short)(u >> 16);
}
__device__ __forceinline__ float bf2f(unsigned short b) {
    return __uint_as_float(((unsigned int)b) << 16);
}
__device__ __forceinline__ unsigned int pk2bf(float a, float b) {
    return (unsigned int)f2bf(a) | ((unsigned int)f2bf(b) << 16);
}
__device__ __forceinline__ float waveReduceSum(float v) {
    #pragma unroll
    for (int off = 32; off; off >>= 1) v += __shfl_xor(v, off, 64);
    return v;
}

// ---------------- mega prep: adj cast | enc_w cast | items prep (incl proto norm) ----------------
__global__ __launch_bounds__(256) void k_mega(const float* __restrict__ adj,
                                              unsigned short* __restrict__ adj_bf,
                                              const float* __restrict__ enc_w,
                                              unsigned short* __restrict__ encw,
                                              const float* __restrict__ item_emb,
                                              const float* __restrict__ proto,
                                              unsigned short* __restrict__ items_bf,
                                              float* __restrict__ catesT) {
    __shared__ float sp[256];
    int bx = blockIdx.x, tid = threadIdx.x;
    if (bx < 33280) {
        const float* src = (bx < 32768) ? adj : enc_w;
        unsigned short* dst = (bx < 32768) ? adj_bf : encw;
        size_t base = (bx < 32768) ? (size_t)bx : (size_t)(bx - 32768);
        size_t i = (base * 256 + tid) * 8;
        float4 a = *(const float4*)(src + i);
        float4 b = *(const float4*)(src + i + 4);
        uint4 pk;
        pk.x = pk2bf(a.x, a.y); pk.y = pk2bf(a.z, a.w);
        pk.z = pk2bf(b.x, b.y); pk.w = pk2bf(b.z, b.w);
        *(uint4*)(dst + i) = pk;
        return;
    }
    // ---- items prep ----
    sp[tid] = proto[tid];
    __syncthreads();
    {
        float v = sp[tid];
        float ss = waveReduceSum(v * v);   // wave w == proto row w
        sp[tid] = v * (1.f / fmaxf(sqrtf(ss), 1e-12f));
    }
    __syncthreads();
    int i = (bx - 33280) * 256 + tid;
    const float4* row = (const float4*)(item_emb + (size_t)i * 64);
    float4 f[16];
    float ss = 0.f;
    #pragma unroll
    for (int q = 0; q < 16; ++q) {
        f[q] = row[q];
        ss += f[q].x * f[q].x + f[q].y * f[q].y + f[q].z * f[q].z + f[q].w * f[q].w;
    }
    float inv = 1.f / fmaxf(sqrtf(ss), 1e-12f);
    float dots[4] = {0.f, 0.f, 0.f, 0.f};
    unsigned short* ob = items_bf + (size_t)i * 64;
    #pragma unroll
    for (int q = 0; q < 16; ++q) {
        f[q].x *= inv; f[q].y *= inv; f[q].z *= inv; f[q].w *= inv;
        #pragma unroll
        for (int k = 0; k < 4; ++k) {
            dots[k] += f[q].x * sp[k * 64 + q * 4 + 0] + f[q].y * sp[k * 64 + q * 4 + 1]
                     + f[q].z * sp[k * 64 + q * 4 + 2] + f[q].w * sp[k * 64 + q * 4 + 3];
        }
    }
    #pragma unroll
    for (int q = 0; q < 16; q += 2) {
        uint4 pk;
        pk.x = pk2bf(f[q].x, f[q].y);         pk.y = pk2bf(f[q].z, f[q].w);
        pk.z = pk2bf(f[q + 1].x, f[q + 1].y); pk.w = pk2bf(f[q + 1].z, f[q + 1].w);
        *(uint4*)(ob + q * 4) = pk;
    }
    float m = fmaxf(fmaxf(dots[0], dots[1]), fmaxf(dots[2], dots[3]));
    float e0 = expf(dots[0] - m), e1 = expf(dots[1] - m), e2 = expf(dots[2] - m), e3 = expf(dots[3] - m);
    float is = 1.f / (e0 + e1 + e2 + e3);
    catesT[0 * 8192 + i] = e0 * is;
    catesT[1 * 8192 + i] = e1 * is;
    catesT[2 * 8192 + i] = e2 * is;
    catesT[3 * 8192 + i] = e3 * is;
}

// ---------------- MFMA GEMM C = A @ B^T (bf16, K-contig), bf16 split-K partials ----------------
__global__ __launch_bounds__(256) void k_gemm_part(const unsigned short* __restrict__ A,
                                                   const unsigned short* __restrict__ B,
                                                   unsigned short* __restrict__ Cout,
                                                   int M, int ksplit, int lda, int ldb, int ldc) {
    __shared__ unsigned short lA[128 * 64];
    __shared__ unsigned short lB[128 * 64];
    int tid = threadIdx.x;
    int lane = tid & 63;
    int w = tid >> 6;
    int wr = w >> 1, wc = w & 1;
    int mBase = blockIdx.y * 128;
    int nBase = blockIdx.x * 128;
    int Kbeg = blockIdx.z * ksplit;
    int Kend = Kbeg + ksplit;

    f32x4 acc[4][4] = {};

    const unsigned short* Ablk = A + (size_t)mBase * lda;
    const unsigned short* Bblk = B + (size_t)nBase * ldb;
    int srow = tid >> 3;
    int scg = (tid & 7) ^ (srow & 7);
    char* ldsA_w = (char*)lA + w * 1024;
    char* ldsB_w = (char*)lB + w * 1024;

    for (int k0 = Kbeg; k0 < Kend; k0 += 64) {
        __syncthreads();
        #pragma unroll
        for (int it = 0; it < 4; ++it) {
            const unsigned short* ga = Ablk + (size_t)(it * 32 + srow) * lda + k0 + scg * 8;
            __builtin_amdgcn_global_load_lds(AS1P(ga), AS3P(ldsA_w + it * 4096), 16, 0, 0);
            const unsigned short* gb = Bblk + (size_t)(it * 32 + srow) * ldb + k0 + scg * 8;
            __builtin_amdgcn_global_load_lds(AS1P(gb), AS3P(ldsB_w + it * 4096), 16, 0, 0);
        }
        __syncthreads();
        #pragma unroll
        for (int kk = 0; kk < 2; ++kk) {
            short8 af[4], bfr[4];
            #pragma unroll
            for (int i = 0; i < 4; ++i) {
                int rowa = wr * 64 + i * 16 + (lane & 15);
                int slot = kk * 4 + (lane >> 4);
                af[i] = *(const short8*)((const char*)lA + rowa * 128 + ((slot ^ (rowa & 7)) * 16));
                int rowb = wc * 64 + i * 16 + (lane & 15);
                bfr[i] = *(const short8*)((const char*)lB + rowb * 128 + ((slot ^ (rowb & 7)) * 16));
            }
            #pragma unroll
            for (int i = 0; i < 4; ++i)
                #pragma unroll
                for (int j = 0; j < 4; ++j)
                    acc[i][j] = __builtin_amdgcn_mfma_f32_16x16x32_bf16(af[i], bfr[j], acc[i][j], 0, 0, 0);
        }
    }

    unsigned short* outP = Cout + (size_t)blockIdx.z * M * ldc;
    #pragma unroll
    for (int i = 0; i < 4; ++i) {
        int rbase = mBase + wr * 64 + i * 16 + (lane >> 4) * 4;
        #pragma unroll
        for (int j = 0; j < 4; ++j) {
            int col = nBase + wc * 64 + j * 16 + (lane & 15);
            #pragma unroll
            for (int r = 0; r < 4; ++r)
                outP[(size_t)(rbase + r) * ldc + col] = f2bf(acc[i][j][r]);
        }
    }
}

// bx<512: sum 16 bf16 partials [sp][128][8192] -> W1T bf16  |  bx>=512: rating cast + inv4
__global__ __launch_bounds__(256) void k_redW(const unsigned short* __restrict__ part,
                                              unsigned short* __restrict__ W1T,
                                              const float* __restrict__ rating,
                                              const float* __restrict__ catesT,
                                              unsigned short* __restrict__ rating_bf,
                                              float* __restrict__ inv4) {
    int tid = threadIdx.x;
    if (blockIdx.x < 512) {
        size_t base = ((size_t)blockIdx.x * 256 + tid) * 8;
        float a[8] = {0.f,0.f,0.f,0.f,0.f,0.f,0.f,0.f};
        #pragma unroll
        for (int sp = 0; sp < 16; ++sp) {
            uint4 v = *(const uint4*)(part + (size_t)sp * 1048576 + base);
            a[0] += bf2f((unsigned short)(v.x & 0xffff)); a[1] += bf2f((unsigned short)(v.x >> 16));
            a[2] += bf2f((unsigned short)(v.y & 0xffff)); a[3] += bf2f((unsigned short)(v.y >> 16));
            a[4] += bf2f((unsigned short)(v.z & 0xffff)); a[5] += bf2f((unsigned short)(v.z >> 16));
            a[6] += bf2f((unsigned short)(v.w & 0xffff)); a[7] += bf2f((unsigned short)(v.w >> 16));
        }
        uint4 pk;
        pk.x = pk2bf(a[0], a[1]); pk.y = pk2bf(a[2], a[3]);
        pk.z = pk2bf(a[4], a[5]); pk.w = pk2bf(a[6], a[7]);
        *(uint4*)(W1T + base) = pk;
        return;
    }
    __shared__ float t[16];
    int b = blockIdx.x - 512;
    const float* row = rating + (size_t)b * 8192;
    float s0 = 0.f, s1 = 0.f, s2 = 0.f, s3 = 0.f;
    #pragma unroll
    for (int j = 0; j < 8; ++j) {
        int i4 = tid + j * 256;
        float4 r = *(const float4*)(row + i4 * 4);
        ushort4 pk;
        pk.x = f2bf(r.x); pk.y = f2bf(r.y); pk.z = f2bf(r.z); pk.w = f2bf(r.w);
        *(ushort4*)(rating_bf + (size_t)b * 8192 + i4 * 4) = pk;
        float4 c0 = *(const float4*)(catesT + 0 * 8192 + i4 * 4);
        float4 c1 = *(const float4*)(catesT + 1 * 8192 + i4 * 4);
        float4 c2 = *(const float4*)(catesT + 2 * 8192 + i4 * 4);
        float4 c3 = *(const float4*)(catesT + 3 * 8192 + i4 * 4);
        float px, py, pz, pw;
        px = r.x * c0.x; py = r.y * c0.y; pz = r.z * c0.z; pw = r.w * c0.w;
        s0 += px * px + py * py + pz * pz + pw * pw;
        px = r.x * c1.x; py = r.y * c1.y; pz = r.z * c1.z; pw = r.w * c1.w;
        s1 += px * px + py * py + pz * pz + pw * pw;
        px = r.x * c2.x; py = r.y * c2.y; pz = r.z * c2.z; pw = r.w * c2.w;
        s2 += px * px + py * py + pz * pz + pw * pw;
        px = r.x * c3.x; py = r.y * c3.y; pz = r.z * c3.z; pw = r.w * c3.w;
        s3 += px * px + py * py + pz * pz + pw * pw;
    }
    s0 = waveReduceSum(s0); s1 = waveReduceSum(s1);
    s2 = waveReduceSum(s2); s3 = waveReduceSum(s3);
    if ((tid & 63) == 0) {
        int w = tid >> 6;
        t[w * 4 + 0] = s0; t[w * 4 + 1] = s1; t[w * 4 + 2] = s2; t[w * 4 + 3] = s3;
    }
    __syncthreads();
    if (tid < 4) {
        float ss = t[0 * 4 + tid] + t[1 * 4 + tid] + t[2 * 4 + tid] + t[3 * 4 + tid];
        inv4[b * 4 + tid] = 1.f / fmaxf(sqrtf(ss), 1e-12f);
    }
}

// sum 16 bf16 partials [sp][128][8192] (=W2T), fold enc_w and cates ->
// G[k*128+o][n] = bf16(cates[k][n] * 0.5*(W2T[o][n]+enc_w[o][n]))
__global__ __launch_bounds__(256) void k_red_G(const unsigned short* __restrict__ part,
                                               const float* __restrict__ enc_w,
                                               const float* __restrict__ catesT,
                                               unsigned short* __restrict__ G) {
    size_t base = ((size_t)blockIdx.x * 256 + threadIdx.x) * 8;
    int o = (int)(base >> 13);
    int n = (int)(base & 8191);
    float a[8] = {0.f,0.f,0.f,0.f,0.f,0.f,0.f,0.f};
    #pragma unroll
    for (int sp = 0; sp < 16; ++sp) {
        uint4 v = *(const uint4*)(part + (size_t)sp * 1048576 + base);
        a[0] += bf2f((unsigned short)(v.x & 0xffff)); a[1] += bf2f((unsigned short)(v.x >> 16));
        a[2] += bf2f((unsigned short)(v.y & 0xffff)); a[3] += bf2f((unsigned short)(v.y >> 16));
        a[4] += bf2f((unsigned short)(v.z & 0xffff)); a[5] += bf2f((unsigned short)(v.z >> 16));
        a[6] += bf2f((unsigned short)(v.w & 0xffff)); a[7] += bf2f((unsigned short)(v.w >> 16));
    }
    float4 e0 = *(const float4*)(enc_w + base);
    float4 e1 = *(const float4*)(enc_w + base + 4);
    a[0] = 0.5f * (a[0] + e0.x); a[1] = 0.5f * (a[1] + e0.y);
    a[2] = 0.5f * (a[2] + e0.z); a[3] = 0.5f * (a[3] + e0.w);
    a[4] = 0.5f * (a[4] + e1.x); a[5] = 0.5f * (a[5] + e1.y);
    a[6] = 0.5f * (a[6] + e1.z); a[7] = 0.5f * (a[7] + e1.w);
    #pragma unroll
    for (int k = 0; k < 4; ++k) {
        float4 c0 = *(const float4*)(catesT + (size_t)k * 8192 + n);
        float4 c1 = *(const float4*)(catesT + (size_t)k * 8192 + n + 4);
        uint4 pk;
        pk.x = pk2bf(a[0] * c0.x, a[1] * c0.y); pk.y = pk2bf(a[2] * c0.z, a[3] * c0.w);
        pk.z = pk2bf(a[4] * c1.x, a[5] * c1.y); pk.w = pk2bf(a[6] * c1.z, a[7] * c1.w);
        *(uint4*)(G + (size_t)(k * 128 + o) * 8192 + n) = pk;
    }
}

// sum 32 bf16 h-partials, scale by inv4, +bias; write mu (f32 + bf16) and logvar
__global__ __launch_bounds__(128) void k_reduce_h2(const unsigned short* __restrict__ hpart,
                                                   const float* __restrict__ enc_b,
                                                   const float* __restrict__ inv4,
                                                   unsigned short* __restrict__ mu_bf,
                                                   float* __restrict__ outp) {
    int r = blockIdx.x;                 // k*512 + b
    int k = r >> 9, b = r & 511;
    int o = threadIdx.x;
    float s = 0.f;
    #pragma unroll
    for (int sp = 0; sp < 32; ++sp)
        s += bf2f(hpart[(size_t)sp * 262144 + (size_t)b * 512 + k * 128 + o]);
    s = s * inv4[b * 4 + k] + enc_b[o];
    const size_t MU0 = (size_t)512 * 8192;
    const size_t LV0 = MU0 + (size_t)2048 * 64;
    if (o < 64) {
        float ss = s * s;
        #pragma unroll
        for (int off = 32; off; off >>= 1) ss += __shfl_xor(ss, off, 64);
        float inv = 1.f / fmaxf(sqrtf(ss), 1e-12f);
        float mv = s * inv;
        outp[MU0 + (size_t)r * 64 + o] = mv;
        mu_bf[(size_t)r * 64 + o] = f2bf(mv);
    } else {
        outp[LV0 + (size_t)r * 64 + (o - 64)] = -s;
    }
}

// MFMA logits: per block 128(b) x 128(n), loop 4 protos; out = log(sum_k exp(z_k . item) * cates_k)
__global__ __launch_bounds__(256) void k_logits_mfma(const unsigned short* __restrict__ mu_bf,
                                                     const unsigned short* __restrict__ items_bf,
                                                     const float* __restrict__ catesT,
                                                     float* __restrict__ out) {
    __shared__ unsigned short lA[128 * 64];
    __shared__ unsigned short lB[128 * 64];
    int tid = threadIdx.x;
    int lane = tid & 63, w = tid >> 6, wr = w >> 1, wc = w & 1;
    int nBase = blockIdx.x * 128, bBase = blockIdx.y * 128;
    int srow = tid >> 3;
    int scg = (tid & 7) ^ (srow & 7);
    char* ldsA_w = (char*)lA + w * 1024;
    char* ldsB_w = (char*)lB + w * 1024;

    #pragma unroll
    for (int it = 0; it < 4; ++it) {
        const unsigned short* gb = items_bf + (size_t)(nBase + it * 32 + srow) * 64 + scg * 8;
        __builtin_amdgcn_global_load_lds(AS1P(gb), AS3P(ldsB_w + it * 4096), 16, 0, 0);
    }

    f32x4 p[4][4] = {};
    for (int k = 0; k < 4; ++k) {
        __syncthreads();
        #pragma unroll
        for (int it = 0; it < 4; ++it) {
            const unsigned short* ga = mu_bf + (size_t)(k * 512 + bBase + it * 32 + srow) * 64 + scg * 8;
            __builtin_amdgcn_global_load_lds(AS1P(ga), AS3P(ldsA_w + it * 4096), 16, 0, 0);
        }
        __syncthreads();
        f32x4 acc[4][4] = {};
        #pragma unroll
        for (int kk = 0; kk < 2; ++kk) {
            short8 af[4], bfr[4];
            #pragma unroll
            for (int i = 0; i < 4; ++i) {
                int rowa = wr * 64 + i * 16 + (lane & 15);
                int slot = kk * 4 + (lane >> 4);
                af[i] = *(const short8*)((const char*)lA + rowa * 128 + ((slot ^ (rowa & 7)) * 16));
                int rowb = wc * 64 + i * 16 + (lane & 15);
                bfr[i] = *(const short8*)((const char*)lB + rowb * 128 + ((slot ^ (rowb & 7)) * 16));
            }
            #pragma unroll
            for (int i = 0; i < 4; ++i)
                #pragma unroll
                for (int j = 0; j < 4; ++j)
                    acc[i][j] = __builtin_amdgcn_mfma_f32_16x16x32_bf16(af[i], bfr[j], acc[i][j], 0, 0, 0);
        }
        #pragma unroll
        for (int j = 0; j < 4; ++j) {
            int col = nBase + wc * 64 + j * 16 + (lane & 15);
            float c = catesT[(size_t)k * 8192 + col];
            #pragma unroll
            for (int i = 0; i < 4; ++i)
                #pragma unroll
                for (int r = 0; r < 4; ++r)
                    p[i][j][r] += __expf(acc[i][j][r]) * c;
        }
    }
    #pragma unroll
    for (int i = 0; i < 4; ++i) {
        int rbase = bBase + wr * 64 + i * 16 + (lane >> 4) * 4;
        #pragma unroll
        for (int j = 0; j < 4; ++j) {
            int col = nBase + wc * 64 + j * 16 + (lane & 15);
            #pragma unroll
            for (int r = 0; r < 4; ++r)
                out[(size_t)(rbase + r) * 8192 + col] = __logf(p[i][j][r]);
        }
    }
}

extern "C" void kernel_launch(void* const* d_in, const int* in_sizes, int n_in,
                              void* d_out, int out_size, void* d_ws, size_t ws_size,
                              hipStream_t stream) {
    const float* rating   = (const float*)d_in[0];   // [512][8192]
    const float* adj      = (const float*)d_in[1];   // [8192][8192]
    const float* item_emb = (const float*)d_in[2];   // [8192][64]
    const float* proto    = (const float*)d_in[3];   // [4][64]
    const float* enc_w    = (const float*)d_in[4];   // [128][8192]
    const float* enc_b    = (const float*)d_in[5];   // [128]
    float* out = (float*)d_out;

    char* ws = (char*)d_ws;
    unsigned short* adj_bf    = (unsigned short*)ws;                      // 128 MiB
    unsigned short* part_bf   = adj_bf + (size_t)8192 * 8192;             // 16*128*8192 bf16 = 32 MiB
    unsigned short* rating_bf = part_bf + (size_t)16 * 1048576;           // 8 MiB
    unsigned short* G         = rating_bf + (size_t)512 * 8192;           // 8 MiB
    unsigned short* W1T       = G + (size_t)512 * 8192;                   // 2 MiB
    unsigned short* encw      = W1T + (size_t)128 * 8192;                 // 2 MiB
    unsigned short* hpart     = encw + (size_t)128 * 8192;                // 32*512*512 bf16 = 16 MiB
    unsigned short* items_bf  = hpart + (size_t)32 * 262144;              // 1 MiB
    unsigned short* mu_bf     = items_bf + (size_t)8192 * 64;             // 0.25 MiB
    float* catesT = (float*)(mu_bf + (size_t)2048 * 64);                  // 4*8192 f32
    float* inv4   = catesT + (size_t)4 * 8192;                            // 2048 f32

    // prep: adj->bf16 (32768 blk) | enc_w->bf16 (512 blk) | items norm+cates (32 blk)
    k_mega<<<33312, 256, 0, stream>>>(adj, adj_bf, enc_w, encw, item_emb, proto, items_bf, catesT);

    // W1T[o][n] partials = encw @ adj_bf^T  (A=encw 128 rows; split-K 16)
    k_gemm_part<<<dim3(64, 1, 16), 256, 0, stream>>>(encw, adj_bf, part_bf, 128, 512, 8192, 8192, 8192);
    // reduce->W1T (512 blk, no transpose) | rating cast + inv4 (512 blk)
    k_redW<<<1024, 256, 0, stream>>>(part_bf, W1T, rating, catesT, rating_bf, inv4);

    // W2T partials = W1T @ adj_bf^T ; reduce folds enc_w + cates -> G
    k_gemm_part<<<dim3(64, 1, 16), 256, 0, stream>>>(W1T, adj_bf, part_bf, 128, 512, 8192, 8192, 8192);
    k_red_G<<<512, 256, 0, stream>>>(part_bf, enc_w, catesT, G);

    // h = rating_bf @ G^T  (split-K 32 -> 512 blocks, 2/CU)
    k_gemm_part<<<dim3(4, 4, 32), 256, 0, stream>>>(rating_bf, G, hpart, 512, 256, 8192, 8192, 512);
    k_reduce_h2<<<2048, 128, 0, stream>>>(hpart, enc_b, inv4, mu_bf, out);

    k_logits_mfma<<<dim3(64, 4), 256, 0, stream>>>(mu_bf, items_bf, catesT, out);
}

// Round 7
// 188.227 us; speedup vs baseline: 1.1886x; 1.0590x over previous
//
#include <hip/hip_runtime.h>

typedef __attribute__((ext_vector_type(8))) short short8;
typedef __attribute__((ext_vector_type(4))) float f32x4;

#define AS3P(x) ((__attribute__((address_space(3))) void*)(x))
#define AS1P(x) ((const __attribute__((address_space(1))) void*)(x))

__device__ __forceinline__ unsigned short f2bf(float f) {
    unsigned int u = __float_as_uint(f);
    u += 0x7fffu + ((u >> 16) & 1u);   // RNE
    return (unsigned short)(u >> 16);
}
__device__ __forceinline__ float bf2f(unsigned short b) {
    return __uint_as_float(((unsigned int)b) << 16);
}
__device__ __forceinline__ unsigned int pk2bf(float a, float b) {
    return (unsigned int)f2bf(a) | ((unsigned int)f2bf(b) << 16);
}
__device__ __forceinline__ float waveReduceSum(float v) {
    #pragma unroll
    for (int off = 32; off; off >>= 1) v += __shfl_xor(v, off, 64);
    return v;
}

// ---------------- mega prep: adj cast | enc_w cast | items prep (incl proto norm) ----------------
__global__ __launch_bounds__(256) void k_mega(const float* __restrict__ adj,
                                              unsigned short* __restrict__ adj_bf,
                                              const float* __restrict__ enc_w,
                                              unsigned short* __restrict__ encw,
                                              const float* __restrict__ item_emb,
                                              const float* __restrict__ proto,
                                              unsigned short* __restrict__ items_bf,
                                              float* __restrict__ catesT) {
    __shared__ float sp[256];
    int bx = blockIdx.x, tid = threadIdx.x;
    if (bx < 33280) {
        const float* src = (bx < 32768) ? adj : enc_w;
        unsigned short* dst = (bx < 32768) ? adj_bf : encw;
        size_t base = (bx < 32768) ? (size_t)bx : (size_t)(bx - 32768);
        size_t i = (base * 256 + tid) * 8;
        float4 a = *(const float4*)(src + i);
        float4 b = *(const float4*)(src + i + 4);
        uint4 pk;
        pk.x = pk2bf(a.x, a.y); pk.y = pk2bf(a.z, a.w);
        pk.z = pk2bf(b.x, b.y); pk.w = pk2bf(b.z, b.w);
        *(uint4*)(dst + i) = pk;
        return;
    }
    // ---- items prep ----
    sp[tid] = proto[tid];
    __syncthreads();
    {
        float v = sp[tid];
        float ss = waveReduceSum(v * v);   // wave w == proto row w
        sp[tid] = v * (1.f / fmaxf(sqrtf(ss), 1e-12f));
    }
    __syncthreads();
    int i = (bx - 33280) * 256 + tid;
    const float4* row = (const float4*)(item_emb + (size_t)i * 64);
    float4 f[16];
    float ss = 0.f;
    #pragma unroll
    for (int q = 0; q < 16; ++q) {
        f[q] = row[q];
        ss += f[q].x * f[q].x + f[q].y * f[q].y + f[q].z * f[q].z + f[q].w * f[q].w;
    }
    float inv = 1.f / fmaxf(sqrtf(ss), 1e-12f);
    float dots[4] = {0.f, 0.f, 0.f, 0.f};
    unsigned short* ob = items_bf + (size_t)i * 64;
    #pragma unroll
    for (int q = 0; q < 16; ++q) {
        f[q].x *= inv; f[q].y *= inv; f[q].z *= inv; f[q].w *= inv;
        #pragma unroll
        for (int k = 0; k < 4; ++k) {
            dots[k] += f[q].x * sp[k * 64 + q * 4 + 0] + f[q].y * sp[k * 64 + q * 4 + 1]
                     + f[q].z * sp[k * 64 + q * 4 + 2] + f[q].w * sp[k * 64 + q * 4 + 3];
        }
    }
    #pragma unroll
    for (int q = 0; q < 16; q += 2) {
        uint4 pk;
        pk.x = pk2bf(f[q].x, f[q].y);         pk.y = pk2bf(f[q].z, f[q].w);
        pk.z = pk2bf(f[q + 1].x, f[q + 1].y); pk.w = pk2bf(f[q + 1].z, f[q + 1].w);
        *(uint4*)(ob + q * 4) = pk;
    }
    float m = fmaxf(fmaxf(dots[0], dots[1]), fmaxf(dots[2], dots[3]));
    float e0 = expf(dots[0] - m), e1 = expf(dots[1] - m), e2 = expf(dots[2] - m), e3 = expf(dots[3] - m);
    float is = 1.f / (e0 + e1 + e2 + e3);
    catesT[0 * 8192 + i] = e0 * is;
    catesT[1 * 8192 + i] = e1 * is;
    catesT[2 * 8192 + i] = e2 * is;
    catesT[3 * 8192 + i] = e3 * is;
}

// ---------------- MFMA GEMM C = A @ B^T (bf16, K-contig), bf16 split-K partials ----------------
__global__ __launch_bounds__(256) void k_gemm_part(const unsigned short* __restrict__ A,
                                                   const unsigned short* __restrict__ B,
                                                   unsigned short* __restrict__ Cout,
                                                   int M, int ksplit, int lda, int ldb, int ldc) {
    __shared__ unsigned short lA[128 * 64];
    __shared__ unsigned short lB[128 * 64];
    int tid = threadIdx.x;
    int lane = tid & 63;
    int w = tid >> 6;
    int wr = w >> 1, wc = w & 1;
    int mBase = blockIdx.y * 128;
    int nBase = blockIdx.x * 128;
    int Kbeg = blockIdx.z * ksplit;
    int Kend = Kbeg + ksplit;

    f32x4 acc[4][4] = {};

    const unsigned short* Ablk = A + (size_t)mBase * lda;
    const unsigned short* Bblk = B + (size_t)nBase * ldb;
    int srow = tid >> 3;
    int scg = (tid & 7) ^ (srow & 7);
    char* ldsA_w = (char*)lA + w * 1024;
    char* ldsB_w = (char*)lB + w * 1024;

    for (int k0 = Kbeg; k0 < Kend; k0 += 64) {
        __syncthreads();
        #pragma unroll
        for (int it = 0; it < 4; ++it) {
            const unsigned short* ga = Ablk + (size_t)(it * 32 + srow) * lda + k0 + scg * 8;
            __builtin_amdgcn_global_load_lds(AS1P(ga), AS3P(ldsA_w + it * 4096), 16, 0, 0);
            const unsigned short* gb = Bblk + (size_t)(it * 32 + srow) * ldb + k0 + scg * 8;
            __builtin_amdgcn_global_load_lds(AS1P(gb), AS3P(ldsB_w + it * 4096), 16, 0, 0);
        }
        __syncthreads();
        #pragma unroll
        for (int kk = 0; kk < 2; ++kk) {
            short8 af[4], bfr[4];
            #pragma unroll
            for (int i = 0; i < 4; ++i) {
                int rowa = wr * 64 + i * 16 + (lane & 15);
                int slot = kk * 4 + (lane >> 4);
                af[i] = *(const short8*)((const char*)lA + rowa * 128 + ((slot ^ (rowa & 7)) * 16));
                int rowb = wc * 64 + i * 16 + (lane & 15);
                bfr[i] = *(const short8*)((const char*)lB + rowb * 128 + ((slot ^ (rowb & 7)) * 16));
            }
            #pragma unroll
            for (int i = 0; i < 4; ++i)
                #pragma unroll
                for (int j = 0; j < 4; ++j)
                    acc[i][j] = __builtin_amdgcn_mfma_f32_16x16x32_bf16(af[i], bfr[j], acc[i][j], 0, 0, 0);
        }
    }

    unsigned short* outP = Cout + (size_t)blockIdx.z * M * ldc;
    #pragma unroll
    for (int i = 0; i < 4; ++i) {
        int rbase = mBase + wr * 64 + i * 16 + (lane >> 4) * 4;
        #pragma unroll
        for (int j = 0; j < 4; ++j) {
            int col = nBase + wc * 64 + j * 16 + (lane & 15);
            #pragma unroll
            for (int r = 0; r < 4; ++r)
                outP[(size_t)(rbase + r) * ldc + col] = f2bf(acc[i][j][r]);
        }
    }
}

// bx<512: sum 8 bf16 partials [sp][128][8192] -> W1T bf16  |  bx>=512: rating cast + inv4
__global__ __launch_bounds__(256) void k_redW(const unsigned short* __restrict__ part,
                                              unsigned short* __restrict__ W1T,
                                              const float* __restrict__ rating,
                                              const float* __restrict__ catesT,
                                              unsigned short* __restrict__ rating_bf,
                                              float* __restrict__ inv4) {
    int tid = threadIdx.x;
    if (blockIdx.x < 512) {
        size_t base = ((size_t)blockIdx.x * 256 + tid) * 8;
        float a[8] = {0.f,0.f,0.f,0.f,0.f,0.f,0.f,0.f};
        #pragma unroll
        for (int sp = 0; sp < 8; ++sp) {
            uint4 v = *(const uint4*)(part + (size_t)sp * 1048576 + base);
            a[0] += bf2f((unsigned short)(v.x & 0xffff)); a[1] += bf2f((unsigned short)(v.x >> 16));
            a[2] += bf2f((unsigned short)(v.y & 0xffff)); a[3] += bf2f((unsigned short)(v.y >> 16));
            a[4] += bf2f((unsigned short)(v.z & 0xffff)); a[5] += bf2f((unsigned short)(v.z >> 16));
            a[6] += bf2f((unsigned short)(v.w & 0xffff)); a[7] += bf2f((unsigned short)(v.w >> 16));
        }
        uint4 pk;
        pk.x = pk2bf(a[0], a[1]); pk.y = pk2bf(a[2], a[3]);
        pk.z = pk2bf(a[4], a[5]); pk.w = pk2bf(a[6], a[7]);
        *(uint4*)(W1T + base) = pk;
        return;
    }
    __shared__ float t[16];
    int b = blockIdx.x - 512;
    const float* row = rating + (size_t)b * 8192;
    float s0 = 0.f, s1 = 0.f, s2 = 0.f, s3 = 0.f;
    #pragma unroll
    for (int j = 0; j < 8; ++j) {
        int i4 = tid + j * 256;
        float4 r = *(const float4*)(row + i4 * 4);
        ushort4 pk;
        pk.x = f2bf(r.x); pk.y = f2bf(r.y); pk.z = f2bf(r.z); pk.w = f2bf(r.w);
        *(ushort4*)(rating_bf + (size_t)b * 8192 + i4 * 4) = pk;
        float4 c0 = *(const float4*)(catesT + 0 * 8192 + i4 * 4);
        float4 c1 = *(const float4*)(catesT + 1 * 8192 + i4 * 4);
        float4 c2 = *(const float4*)(catesT + 2 * 8192 + i4 * 4);
        float4 c3 = *(const float4*)(catesT + 3 * 8192 + i4 * 4);
        float px, py, pz, pw;
        px = r.x * c0.x; py = r.y * c0.y; pz = r.z * c0.z; pw = r.w * c0.w;
        s0 += px * px + py * py + pz * pz + pw * pw;
        px = r.x * c1.x; py = r.y * c1.y; pz = r.z * c1.z; pw = r.w * c1.w;
        s1 += px * px + py * py + pz * pz + pw * pw;
        px = r.x * c2.x; py = r.y * c2.y; pz = r.z * c2.z; pw = r.w * c2.w;
        s2 += px * px + py * py + pz * pz + pw * pw;
        px = r.x * c3.x; py = r.y * c3.y; pz = r.z * c3.z; pw = r.w * c3.w;
        s3 += px * px + py * py + pz * pz + pw * pw;
    }
    s0 = waveReduceSum(s0); s1 = waveReduceSum(s1);
    s2 = waveReduceSum(s2); s3 = waveReduceSum(s3);
    if ((tid & 63) == 0) {
        int w = tid >> 6;
        t[w * 4 + 0] = s0; t[w * 4 + 1] = s1; t[w * 4 + 2] = s2; t[w * 4 + 3] = s3;
    }
    __syncthreads();
    if (tid < 4) {
        float ss = t[0 * 4 + tid] + t[1 * 4 + tid] + t[2 * 4 + tid] + t[3 * 4 + tid];
        inv4[b * 4 + tid] = 1.f / fmaxf(sqrtf(ss), 1e-12f);
    }
}

// sum 8 bf16 partials [sp][128][8192] (=W2T), fold enc_w and cates ->
// G[k*128+o][n] = bf16(cates[k][n] * 0.5*(W2T[o][n]+enc_w[o][n]))
__global__ __launch_bounds__(256) void k_red_G(const unsigned short* __restrict__ part,
                                               const float* __restrict__ enc_w,
                                               const float* __restrict__ catesT,
                                               unsigned short* __restrict__ G) {
    size_t base = ((size_t)blockIdx.x * 256 + threadIdx.x) * 8;
    int o = (int)(base >> 13);
    int n = (int)(base & 8191);
    float a[8] = {0.f,0.f,0.f,0.f,0.f,0.f,0.f,0.f};
    #pragma unroll
    for (int sp = 0; sp < 8; ++sp) {
        uint4 v = *(const uint4*)(part + (size_t)sp * 1048576 + base);
        a[0] += bf2f((unsigned short)(v.x & 0xffff)); a[1] += bf2f((unsigned short)(v.x >> 16));
        a[2] += bf2f((unsigned short)(v.y & 0xffff)); a[3] += bf2f((unsigned short)(v.y >> 16));
        a[4] += bf2f((unsigned short)(v.z & 0xffff)); a[5] += bf2f((unsigned short)(v.z >> 16));
        a[6] += bf2f((unsigned short)(v.w & 0xffff)); a[7] += bf2f((unsigned short)(v.w >> 16));
    }
    float4 e0 = *(const float4*)(enc_w + base);
    float4 e1 = *(const float4*)(enc_w + base + 4);
    a[0] = 0.5f * (a[0] + e0.x); a[1] = 0.5f * (a[1] + e0.y);
    a[2] = 0.5f * (a[2] + e0.z); a[3] = 0.5f * (a[3] + e0.w);
    a[4] = 0.5f * (a[4] + e1.x); a[5] = 0.5f * (a[5] + e1.y);
    a[6] = 0.5f * (a[6] + e1.z); a[7] = 0.5f * (a[7] + e1.w);
    #pragma unroll
    for (int k = 0; k < 4; ++k) {
        float4 c0 = *(const float4*)(catesT + (size_t)k * 8192 + n);
        float4 c1 = *(const float4*)(catesT + (size_t)k * 8192 + n + 4);
        uint4 pk;
        pk.x = pk2bf(a[0] * c0.x, a[1] * c0.y); pk.y = pk2bf(a[2] * c0.z, a[3] * c0.w);
        pk.z = pk2bf(a[4] * c1.x, a[5] * c1.y); pk.w = pk2bf(a[6] * c1.z, a[7] * c1.w);
        *(uint4*)(G + (size_t)(k * 128 + o) * 8192 + n) = pk;
    }
}

// sum 32 bf16 h-partials, scale by inv4, +bias; write mu (f32 + bf16) and logvar
__global__ __launch_bounds__(128) void k_reduce_h2(const unsigned short* __restrict__ hpart,
                                                   const float* __restrict__ enc_b,
                                                   const float* __restrict__ inv4,
                                                   unsigned short* __restrict__ mu_bf,
                                                   float* __restrict__ outp) {
    int r = blockIdx.x;                 // k*512 + b
    int k = r >> 9, b = r & 511;
    int o = threadIdx.x;
    float s = 0.f;
    #pragma unroll
    for (int sp = 0; sp < 32; ++sp)
        s += bf2f(hpart[(size_t)sp * 262144 + (size_t)b * 512 + k * 128 + o]);
    s = s * inv4[b * 4 + k] + enc_b[o];
    const size_t MU0 = (size_t)512 * 8192;
    const size_t LV0 = MU0 + (size_t)2048 * 64;
    if (o < 64) {
        float ss = s * s;
        #pragma unroll
        for (int off = 32; off; off >>= 1) ss += __shfl_xor(ss, off, 64);
        float inv = 1.f / fmaxf(sqrtf(ss), 1e-12f);
        float mv = s * inv;
        outp[MU0 + (size_t)r * 64 + o] = mv;
        mu_bf[(size_t)r * 64 + o] = f2bf(mv);
    } else {
        outp[LV0 + (size_t)r * 64 + (o - 64)] = -s;
    }
}

// MFMA logits: per block 128(b) x 128(n), loop 4 protos; out = log(sum_k exp(z_k . item) * cates_k)
__global__ __launch_bounds__(256) void k_logits_mfma(const unsigned short* __restrict__ mu_bf,
                                                     const unsigned short* __restrict__ items_bf,
                                                     const float* __restrict__ catesT,
                                                     float* __restrict__ out) {
    __shared__ unsigned short lA[128 * 64];
    __shared__ unsigned short lB[128 * 64];
    int tid = threadIdx.x;
    int lane = tid & 63, w = tid >> 6, wr = w >> 1, wc = w & 1;
    int nBase = blockIdx.x * 128, bBase = blockIdx.y * 128;
    int srow = tid >> 3;
    int scg = (tid & 7) ^ (srow & 7);
    char* ldsA_w = (char*)lA + w * 1024;
    char* ldsB_w = (char*)lB + w * 1024;

    #pragma unroll
    for (int it = 0; it < 4; ++it) {
        const unsigned short* gb = items_bf + (size_t)(nBase + it * 32 + srow) * 64 + scg * 8;
        __builtin_amdgcn_global_load_lds(AS1P(gb), AS3P(ldsB_w + it * 4096), 16, 0, 0);
    }

    f32x4 p[4][4] = {};
    for (int k = 0; k < 4; ++k) {
        __syncthreads();
        #pragma unroll
        for (int it = 0; it < 4; ++it) {
            const unsigned short* ga = mu_bf + (size_t)(k * 512 + bBase + it * 32 + srow) * 64 + scg * 8;
            __builtin_amdgcn_global_load_lds(AS1P(ga), AS3P(ldsA_w + it * 4096), 16, 0, 0);
        }
        __syncthreads();
        f32x4 acc[4][4] = {};
        #pragma unroll
        for (int kk = 0; kk < 2; ++kk) {
            short8 af[4], bfr[4];
            #pragma unroll
            for (int i = 0; i < 4; ++i) {
                int rowa = wr * 64 + i * 16 + (lane & 15);
                int slot = kk * 4 + (lane >> 4);
                af[i] = *(const short8*)((const char*)lA + rowa * 128 + ((slot ^ (rowa & 7)) * 16));
                int rowb = wc * 64 + i * 16 + (lane & 15);
                bfr[i] = *(const short8*)((const char*)lB + rowb * 128 + ((slot ^ (rowb & 7)) * 16));
            }
            #pragma unroll
            for (int i = 0; i < 4; ++i)
                #pragma unroll
                for (int j = 0; j < 4; ++j)
                    acc[i][j] = __builtin_amdgcn_mfma_f32_16x16x32_bf16(af[i], bfr[j], acc[i][j], 0, 0, 0);
        }
        #pragma unroll
        for (int j = 0; j < 4; ++j) {
            int col = nBase + wc * 64 + j * 16 + (lane & 15);
            float c = catesT[(size_t)k * 8192 + col];
            #pragma unroll
            for (int i = 0; i < 4; ++i)
                #pragma unroll
                for (int r = 0; r < 4; ++r)
                    p[i][j][r] += __expf(acc[i][j][r]) * c;
        }
    }
    #pragma unroll
    for (int i = 0; i < 4; ++i) {
        int rbase = bBase + wr * 64 + i * 16 + (lane >> 4) * 4;
        #pragma unroll
        for (int j = 0; j < 4; ++j) {
            int col = nBase + wc * 64 + j * 16 + (lane & 15);
            #pragma unroll
            for (int r = 0; r < 4; ++r)
                out[(size_t)(rbase + r) * 8192 + col] = __logf(p[i][j][r]);
        }
    }
}

extern "C" void kernel_launch(void* const* d_in, const int* in_sizes, int n_in,
                              void* d_out, int out_size, void* d_ws, size_t ws_size,
                              hipStream_t stream) {
    const float* rating   = (const float*)d_in[0];   // [512][8192]
    const float* adj      = (const float*)d_in[1];   // [8192][8192]
    const float* item_emb = (const float*)d_in[2];   // [8192][64]
    const float* proto    = (const float*)d_in[3];   // [4][64]
    const float* enc_w    = (const float*)d_in[4];   // [128][8192]
    const float* enc_b    = (const float*)d_in[5];   // [128]
    float* out = (float*)d_out;

    char* ws = (char*)d_ws;
    unsigned short* adj_bf    = (unsigned short*)ws;                      // 128 MiB
    unsigned short* part_bf   = adj_bf + (size_t)8192 * 8192;             // 8*128*8192 bf16 = 16 MiB
    unsigned short* rating_bf = part_bf + (size_t)8 * 1048576;            // 8 MiB
    unsigned short* G         = rating_bf + (size_t)512 * 8192;           // 8 MiB
    unsigned short* W1T       = G + (size_t)512 * 8192;                   // 2 MiB
    unsigned short* encw      = W1T + (size_t)128 * 8192;                 // 2 MiB
    unsigned short* hpart     = encw + (size_t)128 * 8192;                // 32*512*512 bf16 = 16 MiB
    unsigned short* items_bf  = hpart + (size_t)32 * 262144;              // 1 MiB
    unsigned short* mu_bf     = items_bf + (size_t)8192 * 64;             // 0.25 MiB
    float* catesT = (float*)(mu_bf + (size_t)2048 * 64);                  // 4*8192 f32
    float* inv4   = catesT + (size_t)4 * 8192;                            // 2048 f32

    // prep: adj->bf16 (32768 blk) | enc_w->bf16 (512 blk) | items norm+cates (32 blk)
    k_mega<<<33312, 256, 0, stream>>>(adj, adj_bf, enc_w, encw, item_emb, proto, items_bf, catesT);

    // W1T[o][n] partials = encw @ adj_bf^T  (A=encw 128 rows; split-K 8)
    k_gemm_part<<<dim3(64, 1, 8), 256, 0, stream>>>(encw, adj_bf, part_bf, 128, 1024, 8192, 8192, 8192);
    // reduce->W1T (512 blk, no transpose) | rating cast + inv4 (512 blk)
    k_redW<<<1024, 256, 0, stream>>>(part_bf, W1T, rating, catesT, rating_bf, inv4);

    // W2T partials = W1T @ adj_bf^T ; reduce folds enc_w + cates -> G
    k_gemm_part<<<dim3(64, 1, 8), 256, 0, stream>>>(W1T, adj_bf, part_bf, 128, 1024, 8192, 8192, 8192);
    k_red_G<<<512, 256, 0, stream>>>(part_bf, enc_w, catesT, G);

    // h = rating_bf @ G^T  (split-K 32 -> 512 blocks, 2/CU)
    k_gemm_part<<<dim3(4, 4, 32), 256, 0, stream>>>(rating_bf, G, hpart, 512, 256, 8192, 8192, 512);
    k_reduce_h2<<<2048, 128, 0, stream>>>(hpart, enc_b, inv4, mu_bf, out);

    k_logits_mfma<<<dim3(64, 4), 256, 0, stream>>>(mu_bf, items_bf, catesT, out);
}

// Round 9
// 179.672 us; speedup vs baseline: 1.2452x; 1.0476x over previous
//
#include <hip/hip_runtime.h>

typedef __attribute__((ext_vector_type(8))) short short8;
typedef __attribute__((ext_vector_type(4))) float f32x4;

#define AS3P(x) ((__attribute__((address_space(3))) void*)(x))
#define AS1P(x) ((const __attribute__((address_space(1))) void*)(x))

__device__ __forceinline__ unsigned short f2bf(float f) {
    unsigned int u = __float_as_uint(f);
    u += 0x7fffu + ((u >> 16) & 1u);   // RNE
    return (unsigned short)(u >> 16);
}
__device__ __forceinline__ float bf2f(unsigned short b) {
    return __uint_as_float(((unsigned int)b) << 16);
}
__device__ __forceinline__ unsigned int pk2bf(float a, float b) {
    return (unsigned int)f2bf(a) | ((unsigned int)f2bf(b) << 16);
}
__device__ __forceinline__ float waveReduceSum(float v) {
    #pragma unroll
    for (int off = 32; off; off >>= 1) v += __shfl_xor(v, off, 64);
    return v;
}

// ---------------- mega prep: adj cast (nt reads) | enc_w cast | items prep ----------------
__global__ __launch_bounds__(256) void k_mega(const float* __restrict__ adj,
                                              unsigned short* __restrict__ adj_bf,
                                              const float* __restrict__ enc_w,
                                              unsigned short* __restrict__ encw,
                                              const float* __restrict__ item_emb,
                                              const float* __restrict__ proto,
                                              unsigned short* __restrict__ items_bf,
                                              float* __restrict__ catesT) {
    __shared__ float sp[256];
    int bx = blockIdx.x, tid = threadIdx.x;
    if (bx < 32768) {
        // adj cast: NON-TEMPORAL f32 reads (nt -> no L3 allocation) so adj_bf stays L3-resident
        size_t i = ((size_t)bx * 256 + tid) * 8;
        f32x4 a = __builtin_nontemporal_load((const f32x4*)(adj + i));
        f32x4 b = __builtin_nontemporal_load((const f32x4*)(adj + i + 4));
        uint4 pk;
        pk.x = pk2bf(a[0], a[1]); pk.y = pk2bf(a[2], a[3]);
        pk.z = pk2bf(b[0], b[1]); pk.w = pk2bf(b[2], b[3]);
        *(uint4*)(adj_bf + i) = pk;
        return;
    }
    if (bx < 33280) {
        size_t i = (((size_t)bx - 32768) * 256 + tid) * 8;
        float4 a = *(const float4*)(enc_w + i);
        float4 b = *(const float4*)(enc_w + i + 4);
        uint4 pk;
        pk.x = pk2bf(a.x, a.y); pk.y = pk2bf(a.z, a.w);
        pk.z = pk2bf(b.x, b.y); pk.w = pk2bf(b.z, b.w);
        *(uint4*)(encw + i) = pk;
        return;
    }
    // ---- items prep ----
    sp[tid] = proto[tid];
    __syncthreads();
    {
        float v = sp[tid];
        float ss = waveReduceSum(v * v);   // wave w == proto row w
        sp[tid] = v * (1.f / fmaxf(sqrtf(ss), 1e-12f));
    }
    __syncthreads();
    int i = (bx - 33280) * 256 + tid;
    const float4* row = (const float4*)(item_emb + (size_t)i * 64);
    float4 f[16];
    float ss = 0.f;
    #pragma unroll
    for (int q = 0; q < 16; ++q) {
        f[q] = row[q];
        ss += f[q].x * f[q].x + f[q].y * f[q].y + f[q].z * f[q].z + f[q].w * f[q].w;
    }
    float inv = 1.f / fmaxf(sqrtf(ss), 1e-12f);
    float dots[4] = {0.f, 0.f, 0.f, 0.f};
    unsigned short* ob = items_bf + (size_t)i * 64;
    #pragma unroll
    for (int q = 0; q < 16; ++q) {
        f[q].x *= inv; f[q].y *= inv; f[q].z *= inv; f[q].w *= inv;
        #pragma unroll
        for (int k = 0; k < 4; ++k) {
            dots[k] += f[q].x * sp[k * 64 + q * 4 + 0] + f[q].y * sp[k * 64 + q * 4 + 1]
                     + f[q].z * sp[k * 64 + q * 4 + 2] + f[q].w * sp[k * 64 + q * 4 + 3];
        }
    }
    #pragma unroll
    for (int q = 0; q < 16; q += 2) {
        uint4 pk;
        pk.x = pk2bf(f[q].x, f[q].y);         pk.y = pk2bf(f[q].z, f[q].w);
        pk.z = pk2bf(f[q + 1].x, f[q + 1].y); pk.w = pk2bf(f[q + 1].z, f[q + 1].w);
        *(uint4*)(ob + q * 4) = pk;
    }
    float m = fmaxf(fmaxf(dots[0], dots[1]), fmaxf(dots[2], dots[3]));
    float e0 = expf(dots[0] - m), e1 = expf(dots[1] - m), e2 = expf(dots[2] - m), e3 = expf(dots[3] - m);
    float is = 1.f / (e0 + e1 + e2 + e3);
    catesT[0 * 8192 + i] = e0 * is;
    catesT[1 * 8192 + i] = e1 * is;
    catesT[2 * 8192 + i] = e2 * is;
    catesT[3 * 8192 + i] = e3 * is;
}

// ---------------- MFMA GEMM C = A @ B^T (bf16, K-contig), bf16 split-K partials ----------------
__global__ __launch_bounds__(256) void k_gemm_part(const unsigned short* __restrict__ A,
                                                   const unsigned short* __restrict__ B,
                                                   unsigned short* __restrict__ Cout,
                                                   int M, int ksplit, int lda, int ldb, int ldc) {
    __shared__ unsigned short lA[128 * 64];
    __shared__ unsigned short lB[128 * 64];
    int tid = threadIdx.x;
    int lane = tid & 63;
    int w = tid >> 6;
    int wr = w >> 1, wc = w & 1;
    int mBase = blockIdx.y * 128;
    int nBase = blockIdx.x * 128;
    int Kbeg = blockIdx.z * ksplit;
    int Kend = Kbeg + ksplit;

    f32x4 acc[4][4] = {};

    const unsigned short* Ablk = A + (size_t)mBase * lda;
    const unsigned short* Bblk = B + (size_t)nBase * ldb;
    int srow = tid >> 3;
    int scg = (tid & 7) ^ (srow & 7);
    char* ldsA_w = (char*)lA + w * 1024;
    char* ldsB_w = (char*)lB + w * 1024;

    for (int k0 = Kbeg; k0 < Kend; k0 += 64) {
        __syncthreads();
        #pragma unroll
        for (int it = 0; it < 4; ++it) {
            const unsigned short* ga = Ablk + (size_t)(it * 32 + srow) * lda + k0 + scg * 8;
            __builtin_amdgcn_global_load_lds(AS1P(ga), AS3P(ldsA_w + it * 4096), 16, 0, 0);
            const unsigned short* gb = Bblk + (size_t)(it * 32 + srow) * ldb + k0 + scg * 8;
            __builtin_amdgcn_global_load_lds(AS1P(gb), AS3P(ldsB_w + it * 4096), 16, 0, 0);
        }
        __syncthreads();
        #pragma unroll
        for (int kk = 0; kk < 2; ++kk) {
            short8 af[4], bfr[4];
            #pragma unroll
            for (int i = 0; i < 4; ++i) {
                int rowa = wr * 64 + i * 16 + (lane & 15);
                int slot = kk * 4 + (lane >> 4);
                af[i] = *(const short8*)((const char*)lA + rowa * 128 + ((slot ^ (rowa & 7)) * 16));
                int rowb = wc * 64 + i * 16 + (lane & 15);
                bfr[i] = *(const short8*)((const char*)lB + rowb * 128 + ((slot ^ (rowb & 7)) * 16));
            }
            #pragma unroll
            for (int i = 0; i < 4; ++i)
                #pragma unroll
                for (int j = 0; j < 4; ++j)
                    acc[i][j] = __builtin_amdgcn_mfma_f32_16x16x32_bf16(af[i], bfr[j], acc[i][j], 0, 0, 0);
        }
    }

    unsigned short* outP = Cout + (size_t)blockIdx.z * M * ldc;
    #pragma unroll
    for (int i = 0; i < 4; ++i) {
        int rbase = mBase + wr * 64 + i * 16 + (lane >> 4) * 4;
        #pragma unroll
        for (int j = 0; j < 4; ++j) {
            int col = nBase + wc * 64 + j * 16 + (lane & 15);
            #pragma unroll
            for (int r = 0; r < 4; ++r)
                outP[(size_t)(rbase + r) * ldc + col] = f2bf(acc[i][j][r]);
        }
    }
}

// bx<512: sum 8 bf16 partials [sp][128][8192] -> W1T bf16  |  bx>=512: rating cast + inv4
__global__ __launch_bounds__(256) void k_redW(const unsigned short* __restrict__ part,
                                              unsigned short* __restrict__ W1T,
                                              const float* __restrict__ rating,
                                              const float* __restrict__ catesT,
                                              unsigned short* __restrict__ rating_bf,
                                              float* __restrict__ inv4) {
    int tid = threadIdx.x;
    if (blockIdx.x < 512) {
        size_t base = ((size_t)blockIdx.x * 256 + tid) * 8;
        float a[8] = {0.f,0.f,0.f,0.f,0.f,0.f,0.f,0.f};
        #pragma unroll
        for (int sp = 0; sp < 8; ++sp) {
            uint4 v = *(const uint4*)(part + (size_t)sp * 1048576 + base);
            a[0] += bf2f((unsigned short)(v.x & 0xffff)); a[1] += bf2f((unsigned short)(v.x >> 16));
            a[2] += bf2f((unsigned short)(v.y & 0xffff)); a[3] += bf2f((unsigned short)(v.y >> 16));
            a[4] += bf2f((unsigned short)(v.z & 0xffff)); a[5] += bf2f((unsigned short)(v.z >> 16));
            a[6] += bf2f((unsigned short)(v.w & 0xffff)); a[7] += bf2f((unsigned short)(v.w >> 16));
        }
        uint4 pk;
        pk.x = pk2bf(a[0], a[1]); pk.y = pk2bf(a[2], a[3]);
        pk.z = pk2bf(a[4], a[5]); pk.w = pk2bf(a[6], a[7]);
        *(uint4*)(W1T + base) = pk;
        return;
    }
    __shared__ float t[16];
    int b = blockIdx.x - 512;
    const float* row = rating + (size_t)b * 8192;
    float s0 = 0.f, s1 = 0.f, s2 = 0.f, s3 = 0.f;
    #pragma unroll
    for (int j = 0; j < 8; ++j) {
        int i4 = tid + j * 256;
        f32x4 r = __builtin_nontemporal_load((const f32x4*)(row + i4 * 4));
        ushort4 pk;
        pk.x = f2bf(r[0]); pk.y = f2bf(r[1]); pk.z = f2bf(r[2]); pk.w = f2bf(r[3]);
        *(ushort4*)(rating_bf + (size_t)b * 8192 + i4 * 4) = pk;
        float4 c0 = *(const float4*)(catesT + 0 * 8192 + i4 * 4);
        float4 c1 = *(const float4*)(catesT + 1 * 8192 + i4 * 4);
        float4 c2 = *(const float4*)(catesT + 2 * 8192 + i4 * 4);
        float4 c3 = *(const float4*)(catesT + 3 * 8192 + i4 * 4);
        float px, py, pz, pw;
        px = r[0] * c0.x; py = r[1] * c0.y; pz = r[2] * c0.z; pw = r[3] * c0.w;
        s0 += px * px + py * py + pz * pz + pw * pw;
        px = r[0] * c1.x; py = r[1] * c1.y; pz = r[2] * c1.z; pw = r[3] * c1.w;
        s1 += px * px + py * py + pz * pz + pw * pw;
        px = r[0] * c2.x; py = r[1] * c2.y; pz = r[2] * c2.z; pw = r[3] * c2.w;
        s2 += px * px + py * py + pz * pz + pw * pw;
        px = r[0] * c3.x; py = r[1] * c3.y; pz = r[2] * c3.z; pw = r[3] * c3.w;
        s3 += px * px + py * py + pz * pz + pw * pw;
    }
    s0 = waveReduceSum(s0); s1 = waveReduceSum(s1);
    s2 = waveReduceSum(s2); s3 = waveReduceSum(s3);
    if ((tid & 63) == 0) {
        int w = tid >> 6;
        t[w * 4 + 0] = s0; t[w * 4 + 1] = s1; t[w * 4 + 2] = s2; t[w * 4 + 3] = s3;
    }
    __syncthreads();
    if (tid < 4) {
        float ss = t[0 * 4 + tid] + t[1 * 4 + tid] + t[2 * 4 + tid] + t[3 * 4 + tid];
        inv4[b * 4 + tid] = 1.f / fmaxf(sqrtf(ss), 1e-12f);
    }
}

// sum 8 bf16 partials [sp][128][8192] (=W2T), fold enc_w and cates ->
// G[k*128+o][n] = bf16(cates[k][n] * 0.5*(W2T[o][n]+enc_w[o][n]))
__global__ __launch_bounds__(256) void k_red_G(const unsigned short* __restrict__ part,
                                               const float* __restrict__ enc_w,
                                               const float* __restrict__ catesT,
                                               unsigned short* __restrict__ G) {
    size_t base = ((size_t)blockIdx.x * 256 + threadIdx.x) * 8;
    int o = (int)(base >> 13);
    int n = (int)(base & 8191);
    float a[8] = {0.f,0.f,0.f,0.f,0.f,0.f,0.f,0.f};
    #pragma unroll
    for (int sp = 0; sp < 8; ++sp) {
        uint4 v = *(const uint4*)(part + (size_t)sp * 1048576 + base);
        a[0] += bf2f((unsigned short)(v.x & 0xffff)); a[1] += bf2f((unsigned short)(v.x >> 16));
        a[2] += bf2f((unsigned short)(v.y & 0xffff)); a[3] += bf2f((unsigned short)(v.y >> 16));
        a[4] += bf2f((unsigned short)(v.z & 0xffff)); a[5] += bf2f((unsigned short)(v.z >> 16));
        a[6] += bf2f((unsigned short)(v.w & 0xffff)); a[7] += bf2f((unsigned short)(v.w >> 16));
    }
    float4 e0 = *(const float4*)(enc_w + base);
    float4 e1 = *(const float4*)(enc_w + base + 4);
    a[0] = 0.5f * (a[0] + e0.x); a[1] = 0.5f * (a[1] + e0.y);
    a[2] = 0.5f * (a[2] + e0.z); a[3] = 0.5f * (a[3] + e0.w);
    a[4] = 0.5f * (a[4] + e1.x); a[5] = 0.5f * (a[5] + e1.y);
    a[6] = 0.5f * (a[6] + e1.z); a[7] = 0.5f * (a[7] + e1.w);
    #pragma unroll
    for (int k = 0; k < 4; ++k) {
        float4 c0 = *(const float4*)(catesT + (size_t)k * 8192 + n);
        float4 c1 = *(const float4*)(catesT + (size_t)k * 8192 + n + 4);
        uint4 pk;
        pk.x = pk2bf(a[0] * c0.x, a[1] * c0.y); pk.y = pk2bf(a[2] * c0.z, a[3] * c0.w);
        pk.z = pk2bf(a[4] * c1.x, a[5] * c1.y); pk.w = pk2bf(a[6] * c1.z, a[7] * c1.w);
        *(uint4*)(G + (size_t)(k * 128 + o) * 8192 + n) = pk;
    }
}

// sum 32 bf16 h-partials, scale by inv4, +bias; write mu (f32 + bf16) and logvar
__global__ __launch_bounds__(128) void k_reduce_h2(const unsigned short* __restrict__ hpart,
                                                   const float* __restrict__ enc_b,
                                                   const float* __restrict__ inv4,
                                                   unsigned short* __restrict__ mu_bf,
                                                   float* __restrict__ outp) {
    int r = blockIdx.x;                 // k*512 + b
    int k = r >> 9, b = r & 511;
    int o = threadIdx.x;
    float s = 0.f;
    #pragma unroll
    for (int sp = 0; sp < 32; ++sp)
        s += bf2f(hpart[(size_t)sp * 262144 + (size_t)b * 512 + k * 128 + o]);
    s = s * inv4[b * 4 + k] + enc_b[o];
    const size_t MU0 = (size_t)512 * 8192;
    const size_t LV0 = MU0 + (size_t)2048 * 64;
    if (o < 64) {
        float ss = s * s;
        #pragma unroll
        for (int off = 32; off; off >>= 1) ss += __shfl_xor(ss, off, 64);
        float inv = 1.f / fmaxf(sqrtf(ss), 1e-12f);
        float mv = s * inv;
        outp[MU0 + (size_t)r * 64 + o] = mv;
        mu_bf[(size_t)r * 64 + o] = f2bf(mv);
    } else {
        outp[LV0 + (size_t)r * 64 + (o - 64)] = -s;
    }
}

// MFMA logits: per block 128(b) x 128(n), loop 4 protos; out = log(sum_k exp(z_k . item) * cates_k)
__global__ __launch_bounds__(256) void k_logits_mfma(const unsigned short* __restrict__ mu_bf,
                                                     const unsigned short* __restrict__ items_bf,
                                                     const float* __restrict__ catesT,
                                                     float* __restrict__ out) {
    __shared__ unsigned short lA[128 * 64];
    __shared__ unsigned short lB[128 * 64];
    int tid = threadIdx.x;
    int lane = tid & 63, w = tid >> 6, wr = w >> 1, wc = w & 1;
    int nBase = blockIdx.x * 128, bBase = blockIdx.y * 128;
    int srow = tid >> 3;
    int scg = (tid & 7) ^ (srow & 7);
    char* ldsA_w = (char*)lA + w * 1024;
    char* ldsB_w = (char*)lB + w * 1024;

    #pragma unroll
    for (int it = 0; it < 4; ++it) {
        const unsigned short* gb = items_bf + (size_t)(nBase + it * 32 + srow) * 64 + scg * 8;
        __builtin_amdgcn_global_load_lds(AS1P(gb), AS3P(ldsB_w + it * 4096), 16, 0, 0);
    }

    f32x4 p[4][4] = {};
    for (int k = 0; k < 4; ++k) {
        __syncthreads();
        #pragma unroll
        for (int it = 0; it < 4; ++it) {
            const unsigned short* ga = mu_bf + (size_t)(k * 512 + bBase + it * 32 + srow) * 64 + scg * 8;
            __builtin_amdgcn_global_load_lds(AS1P(ga), AS3P(ldsA_w + it * 4096), 16, 0, 0);
        }
        __syncthreads();
        f32x4 acc[4][4] = {};
        #pragma unroll
        for (int kk = 0; kk < 2; ++kk) {
            short8 af[4], bfr[4];
            #pragma unroll
            for (int i = 0; i < 4; ++i) {
                int rowa = wr * 64 + i * 16 + (lane & 15);
                int slot = kk * 4 + (lane >> 4);
                af[i] = *(const short8*)((const char*)lA + rowa * 128 + ((slot ^ (rowa & 7)) * 16));
                int rowb = wc * 64 + i * 16 + (lane & 15);
                bfr[i] = *(const short8*)((const char*)lB + rowb * 128 + ((slot ^ (rowb & 7)) * 16));
            }
            #pragma unroll
            for (int i = 0; i < 4; ++i)
                #pragma unroll
                for (int j = 0; j < 4; ++j)
                    acc[i][j] = __builtin_amdgcn_mfma_f32_16x16x32_bf16(af[i], bfr[j], acc[i][j], 0, 0, 0);
        }
        #pragma unroll
        for (int j = 0; j < 4; ++j) {
            int col = nBase + wc * 64 + j * 16 + (lane & 15);
            float c = catesT[(size_t)k * 8192 + col];
            #pragma unroll
            for (int i = 0; i < 4; ++i)
                #pragma unroll
                for (int r = 0; r < 4; ++r)
                    p[i][j][r] += __expf(acc[i][j][r]) * c;
        }
    }
    #pragma unroll
    for (int i = 0; i < 4; ++i) {
        int rbase = bBase + wr * 64 + i * 16 + (lane >> 4) * 4;
        #pragma unroll
        for (int j = 0; j < 4; ++j) {
            int col = nBase + wc * 64 + j * 16 + (lane & 15);
            #pragma unroll
            for (int r = 0; r < 4; ++r)
                out[(size_t)(rbase + r) * 8192 + col] = __logf(p[i][j][r]);
        }
    }
}

extern "C" void kernel_launch(void* const* d_in, const int* in_sizes, int n_in,
                              void* d_out, int out_size, void* d_ws, size_t ws_size,
                              hipStream_t stream) {
    const float* rating   = (const float*)d_in[0];   // [512][8192]
    const float* adj      = (const float*)d_in[1];   // [8192][8192]
    const float* item_emb = (const float*)d_in[2];   // [8192][64]
    const float* proto    = (const float*)d_in[3];   // [4][64]
    const float* enc_w    = (const float*)d_in[4];   // [128][8192]
    const float* enc_b    = (const float*)d_in[5];   // [128]
    float* out = (float*)d_out;

    char* ws = (char*)d_ws;
    unsigned short* adj_bf    = (unsigned short*)ws;                      // 128 MiB
    unsigned short* part_bf   = adj_bf + (size_t)8192 * 8192;             // 8*128*8192 bf16 = 16 MiB
    unsigned short* rating_bf = part_bf + (size_t)8 * 1048576;            // 8 MiB
    unsigned short* G         = rating_bf + (size_t)512 * 8192;           // 8 MiB
    unsigned short* W1T       = G + (size_t)512 * 8192;                   // 2 MiB
    unsigned short* encw      = W1T + (size_t)128 * 8192;                 // 2 MiB
    unsigned short* hpart     = encw + (size_t)128 * 8192;                // 32*512*512 bf16 = 16 MiB
    unsigned short* items_bf  = hpart + (size_t)32 * 262144;              // 1 MiB
    unsigned short* mu_bf     = items_bf + (size_t)8192 * 64;             // 0.25 MiB
    float* catesT = (float*)(mu_bf + (size_t)2048 * 64);                  // 4*8192 f32
    float* inv4   = catesT + (size_t)4 * 8192;                            // 2048 f32

    // prep: adj->bf16 nt-read (32768 blk) | enc_w->bf16 (512 blk) | items norm+cates (32 blk)
    k_mega<<<33312, 256, 0, stream>>>(adj, adj_bf, enc_w, encw, item_emb, proto, items_bf, catesT);

    // W1T[o][n] partials = encw @ adj_bf^T  (A=encw 128 rows; split-K 8)
    k_gemm_part<<<dim3(64, 1, 8), 256, 0, stream>>>(encw, adj_bf, part_bf, 128, 1024, 8192, 8192, 8192);
    // reduce->W1T (512 blk, no transpose) | rating cast + inv4 (512 blk)
    k_redW<<<1024, 256, 0, stream>>>(part_bf, W1T, rating, catesT, rating_bf, inv4);

    // W2T partials = W1T @ adj_bf^T ; reduce folds enc_w + cates -> G
    k_gemm_part<<<dim3(64, 1, 8), 256, 0, stream>>>(W1T, adj_bf, part_bf, 128, 1024, 8192, 8192, 8192);
    k_red_G<<<512, 256, 0, stream>>>(part_bf, enc_w, catesT, G);

    // h = rating_bf @ G^T  (split-K 32 -> 512 blocks, 2/CU)
    k_gemm_part<<<dim3(4, 4, 32), 256, 0, stream>>>(rating_bf, G, hpart, 512, 256, 8192, 8192, 512);
    k_reduce_h2<<<2048, 128, 0, stream>>>(hpart, enc_b, inv4, mu_bf, out);

    k_logits_mfma<<<dim3(64, 4), 256, 0, stream>>>(mu_bf, items_bf, catesT, out);
}

// Round 10
// 175.046 us; speedup vs baseline: 1.2781x; 1.0264x over previous
//
#include <hip/hip_runtime.h>

typedef __attribute__((ext_vector_type(8))) short short8;
typedef __attribute__((ext_vector_type(4))) float f32x4;

#define AS3P(x) ((__attribute__((address_space(3))) void*)(x))
#define AS1P(x) ((const __attribute__((address_space(1))) void*)(x))

__device__ __forceinline__ unsigned short f2bf(float f) {
    unsigned int u = __float_as_uint(f);
    u += 0x7fffu + ((u >> 16) & 1u);   // RNE
    return (unsigned short)(u >> 16);
}
__device__ __forceinline__ float bf2f(unsigned short b) {
    return __uint_as_float(((unsigned int)b) << 16);
}
__device__ __forceinline__ unsigned int pk2bf(float a, float b) {
    return (unsigned int)f2bf(a) | ((unsigned int)f2bf(b) << 16);
}
__device__ __forceinline__ float waveReduceSum(float v) {
    #pragma unroll
    for (int off = 32; off; off >>= 1) v += __shfl_xor(v, off, 64);
    return v;
}

// ---------------- mega prep: adj cast (nt reads) | enc_w cast | items prep ----------------
__global__ __launch_bounds__(256) void k_mega(const float* __restrict__ adj,
                                              unsigned short* __restrict__ adj_bf,
                                              const float* __restrict__ enc_w,
                                              unsigned short* __restrict__ encw,
                                              const float* __restrict__ item_emb,
                                              const float* __restrict__ proto,
                                              unsigned short* __restrict__ items_bf,
                                              float* __restrict__ catesT) {
    __shared__ float sp[256];
    int bx = blockIdx.x, tid = threadIdx.x;
    if (bx < 32768) {
        // adj cast: NON-TEMPORAL f32 reads (nt -> no L3 allocation) so adj_bf stays L3-resident
        size_t i = ((size_t)bx * 256 + tid) * 8;
        f32x4 a = __builtin_nontemporal_load((const f32x4*)(adj + i));
        f32x4 b = __builtin_nontemporal_load((const f32x4*)(adj + i + 4));
        uint4 pk;
        pk.x = pk2bf(a[0], a[1]); pk.y = pk2bf(a[2], a[3]);
        pk.z = pk2bf(b[0], b[1]); pk.w = pk2bf(b[2], b[3]);
        *(uint4*)(adj_bf + i) = pk;
        return;
    }
    if (bx < 33280) {
        size_t i = (((size_t)bx - 32768) * 256 + tid) * 8;
        float4 a = *(const float4*)(enc_w + i);
        float4 b = *(const float4*)(enc_w + i + 4);
        uint4 pk;
        pk.x = pk2bf(a.x, a.y); pk.y = pk2bf(a.z, a.w);
        pk.z = pk2bf(b.x, b.y); pk.w = pk2bf(b.z, b.w);
        *(uint4*)(encw + i) = pk;
        return;
    }
    // ---- items prep ----
    sp[tid] = proto[tid];
    __syncthreads();
    {
        float v = sp[tid];
        float ss = waveReduceSum(v * v);   // wave w == proto row w
        sp[tid] = v * (1.f / fmaxf(sqrtf(ss), 1e-12f));
    }
    __syncthreads();
    int i = (bx - 33280) * 256 + tid;
    const float4* row = (const float4*)(item_emb + (size_t)i * 64);
    float4 f[16];
    float ss = 0.f;
    #pragma unroll
    for (int q = 0; q < 16; ++q) {
        f[q] = row[q];
        ss += f[q].x * f[q].x + f[q].y * f[q].y + f[q].z * f[q].z + f[q].w * f[q].w;
    }
    float inv = 1.f / fmaxf(sqrtf(ss), 1e-12f);
    float dots[4] = {0.f, 0.f, 0.f, 0.f};
    unsigned short* ob = items_bf + (size_t)i * 64;
    #pragma unroll
    for (int q = 0; q < 16; ++q) {
        f[q].x *= inv; f[q].y *= inv; f[q].z *= inv; f[q].w *= inv;
        #pragma unroll
        for (int k = 0; k < 4; ++k) {
            dots[k] += f[q].x * sp[k * 64 + q * 4 + 0] + f[q].y * sp[k * 64 + q * 4 + 1]
                     + f[q].z * sp[k * 64 + q * 4 + 2] + f[q].w * sp[k * 64 + q * 4 + 3];
        }
    }
    #pragma unroll
    for (int q = 0; q < 16; q += 2) {
        uint4 pk;
        pk.x = pk2bf(f[q].x, f[q].y);         pk.y = pk2bf(f[q].z, f[q].w);
        pk.z = pk2bf(f[q + 1].x, f[q + 1].y); pk.w = pk2bf(f[q + 1].z, f[q + 1].w);
        *(uint4*)(ob + q * 4) = pk;
    }
    float m = fmaxf(fmaxf(dots[0], dots[1]), fmaxf(dots[2], dots[3]));
    float e0 = expf(dots[0] - m), e1 = expf(dots[1] - m), e2 = expf(dots[2] - m), e3 = expf(dots[3] - m);
    float is = 1.f / (e0 + e1 + e2 + e3);
    catesT[0 * 8192 + i] = e0 * is;
    catesT[1 * 8192 + i] = e1 * is;
    catesT[2 * 8192 + i] = e2 * is;
    catesT[3 * 8192 + i] = e3 * is;
}

// ---------------- MFMA GEMM C = A @ B^T (bf16, K-contig), bf16 split-K partials ----------------
// T3-minimal 2-phase: double-buffered LDS, next-tile global_load_lds issued BEFORE
// current-tile ds_read+MFMA; single vmcnt(0)+barrier (__syncthreads) per K-step.
__global__ __launch_bounds__(256) void k_gemm_part(const unsigned short* __restrict__ A,
                                                   const unsigned short* __restrict__ B,
                                                   unsigned short* __restrict__ Cout,
                                                   int M, int ksplit, int lda, int ldb, int ldc) {
    __shared__ unsigned short lA[2][128 * 64];
    __shared__ unsigned short lB[2][128 * 64];
    int tid = threadIdx.x;
    int lane = tid & 63;
    int w = tid >> 6;
    int wr = w >> 1, wc = w & 1;
    int mBase = blockIdx.y * 128;
    int nBase = blockIdx.x * 128;
    int Kbeg = blockIdx.z * ksplit;
    int Kend = Kbeg + ksplit;

    f32x4 acc[4][4] = {};

    const unsigned short* Ablk = A + (size_t)mBase * lda;
    const unsigned short* Bblk = B + (size_t)nBase * ldb;
    int srow = tid >> 3;
    int scg = (tid & 7) ^ (srow & 7);

    // stage K-tile k0 into buffer buf
    #define STAGE(buf, k0)                                                                     \
        do {                                                                                   \
            char* ldsA_w = (char*)lA[buf] + w * 1024;                                          \
            char* ldsB_w = (char*)lB[buf] + w * 1024;                                          \
            _Pragma("unroll")                                                                  \
            for (int it = 0; it < 4; ++it) {                                                   \
                const unsigned short* ga = Ablk + (size_t)(it * 32 + srow) * lda + (k0) + scg * 8; \
                __builtin_amdgcn_global_load_lds(AS1P(ga), AS3P(ldsA_w + it * 4096), 16, 0, 0);    \
                const unsigned short* gb = Bblk + (size_t)(it * 32 + srow) * ldb + (k0) + scg * 8; \
                __builtin_amdgcn_global_load_lds(AS1P(gb), AS3P(ldsB_w + it * 4096), 16, 0, 0);    \
            }                                                                                  \
        } while (0)

    STAGE(0, Kbeg);
    __syncthreads();               // drains vmcnt(0): buf0 ready
    int cur = 0;
    for (int k0 = Kbeg; k0 < Kend; k0 += 64) {
        if (k0 + 64 < Kend) STAGE(cur ^ 1, k0 + 64);   // issue next-tile loads (in flight across compute)
        #pragma unroll
        for (int kk = 0; kk < 2; ++kk) {
            short8 af[4], bfr[4];
            #pragma unroll
            for (int i = 0; i < 4; ++i) {
                int rowa = wr * 64 + i * 16 + (lane & 15);
                int slot = kk * 4 + (lane >> 4);
                af[i] = *(const short8*)((const char*)lA[cur] + rowa * 128 + ((slot ^ (rowa & 7)) * 16));
                int rowb = wc * 64 + i * 16 + (lane & 15);
                bfr[i] = *(const short8*)((const char*)lB[cur] + rowb * 128 + ((slot ^ (rowb & 7)) * 16));
            }
            #pragma unroll
            for (int i = 0; i < 4; ++i)
                #pragma unroll
                for (int j = 0; j < 4; ++j)
                    acc[i][j] = __builtin_amdgcn_mfma_f32_16x16x32_bf16(af[i], bfr[j], acc[i][j], 0, 0, 0);
        }
        __syncthreads();           // vmcnt(0)+lgkmcnt(0): next buf landed, cur free for overwrite
        cur ^= 1;
    }
    #undef STAGE

    unsigned short* outP = Cout + (size_t)blockIdx.z * M * ldc;
    #pragma unroll
    for (int i = 0; i < 4; ++i) {
        int rbase = mBase + wr * 64 + i * 16 + (lane >> 4) * 4;
        #pragma unroll
        for (int j = 0; j < 4; ++j) {
            int col = nBase + wc * 64 + j * 16 + (lane & 15);
            #pragma unroll
            for (int r = 0; r < 4; ++r)
                outP[(size_t)(rbase + r) * ldc + col] = f2bf(acc[i][j][r]);
        }
    }
}

// bx<512: sum 8 bf16 partials [sp][128][8192] -> W1T bf16  |  bx>=512: rating cast + inv4
__global__ __launch_bounds__(256) void k_redW(const unsigned short* __restrict__ part,
                                              unsigned short* __restrict__ W1T,
                                              const float* __restrict__ rating,
                                              const float* __restrict__ catesT,
                                              unsigned short* __restrict__ rating_bf,
                                              float* __restrict__ inv4) {
    int tid = threadIdx.x;
    if (blockIdx.x < 512) {
        size_t base = ((size_t)blockIdx.x * 256 + tid) * 8;
        float a[8] = {0.f,0.f,0.f,0.f,0.f,0.f,0.f,0.f};
        #pragma unroll
        for (int sp = 0; sp < 8; ++sp) {
            uint4 v = *(const uint4*)(part + (size_t)sp * 1048576 + base);
            a[0] += bf2f((unsigned short)(v.x & 0xffff)); a[1] += bf2f((unsigned short)(v.x >> 16));
            a[2] += bf2f((unsigned short)(v.y & 0xffff)); a[3] += bf2f((unsigned short)(v.y >> 16));
            a[4] += bf2f((unsigned short)(v.z & 0xffff)); a[5] += bf2f((unsigned short)(v.z >> 16));
            a[6] += bf2f((unsigned short)(v.w & 0xffff)); a[7] += bf2f((unsigned short)(v.w >> 16));
        }
        uint4 pk;
        pk.x = pk2bf(a[0], a[1]); pk.y = pk2bf(a[2], a[3]);
        pk.z = pk2bf(a[4], a[5]); pk.w = pk2bf(a[6], a[7]);
        *(uint4*)(W1T + base) = pk;
        return;
    }
    __shared__ float t[16];
    int b = blockIdx.x - 512;
    const float* row = rating + (size_t)b * 8192;
    float s0 = 0.f, s1 = 0.f, s2 = 0.f, s3 = 0.f;
    #pragma unroll
    for (int j = 0; j < 8; ++j) {
        int i4 = tid + j * 256;
        f32x4 r = __builtin_nontemporal_load((const f32x4*)(row + i4 * 4));
        ushort4 pk;
        pk.x = f2bf(r[0]); pk.y = f2bf(r[1]); pk.z = f2bf(r[2]); pk.w = f2bf(r[3]);
        *(ushort4*)(rating_bf + (size_t)b * 8192 + i4 * 4) = pk;
        float4 c0 = *(const float4*)(catesT + 0 * 8192 + i4 * 4);
        float4 c1 = *(const float4*)(catesT + 1 * 8192 + i4 * 4);
        float4 c2 = *(const float4*)(catesT + 2 * 8192 + i4 * 4);
        float4 c3 = *(const float4*)(catesT + 3 * 8192 + i4 * 4);
        float px, py, pz, pw;
        px = r[0] * c0.x; py = r[1] * c0.y; pz = r[2] * c0.z; pw = r[3] * c0.w;
        s0 += px * px + py * py + pz * pz + pw * pw;
        px = r[0] * c1.x; py = r[1] * c1.y; pz = r[2] * c1.z; pw = r[3] * c1.w;
        s1 += px * px + py * py + pz * pz + pw * pw;
        px = r[0] * c2.x; py = r[1] * c2.y; pz = r[2] * c2.z; pw = r[3] * c2.w;
        s2 += px * px + py * py + pz * pz + pw * pw;
        px = r[0] * c3.x; py = r[1] * c3.y; pz = r[2] * c3.z; pw = r[3] * c3.w;
        s3 += px * px + py * py + pz * pz + pw * pw;
    }
    s0 = waveReduceSum(s0); s1 = waveReduceSum(s1);
    s2 = waveReduceSum(s2); s3 = waveReduceSum(s3);
    if ((tid & 63) == 0) {
        int w = tid >> 6;
        t[w * 4 + 0] = s0; t[w * 4 + 1] = s1; t[w * 4 + 2] = s2; t[w * 4 + 3] = s3;
    }
    __syncthreads();
    if (tid < 4) {
        float ss = t[0 * 4 + tid] + t[1 * 4 + tid] + t[2 * 4 + tid] + t[3 * 4 + tid];
        inv4[b * 4 + tid] = 1.f / fmaxf(sqrtf(ss), 1e-12f);
    }
}

// sum 8 bf16 partials [sp][128][8192] (=W2T), fold enc_w and cates ->
// G[k*128+o][n] = bf16(cates[k][n] * 0.5*(W2T[o][n]+enc_w[o][n]))
__global__ __launch_bounds__(256) void k_red_G(const unsigned short* __restrict__ part,
                                               const float* __restrict__ enc_w,
                                               const float* __restrict__ catesT,
                                               unsigned short* __restrict__ G) {
    size_t base = ((size_t)blockIdx.x * 256 + threadIdx.x) * 8;
    int o = (int)(base >> 13);
    int n = (int)(base & 8191);
    float a[8] = {0.f,0.f,0.f,0.f,0.f,0.f,0.f,0.f};
    #pragma unroll
    for (int sp = 0; sp < 8; ++sp) {
        uint4 v = *(const uint4*)(part + (size_t)sp * 1048576 + base);
        a[0] += bf2f((unsigned short)(v.x & 0xffff)); a[1] += bf2f((unsigned short)(v.x >> 16));
        a[2] += bf2f((unsigned short)(v.y & 0xffff)); a[3] += bf2f((unsigned short)(v.y >> 16));
        a[4] += bf2f((unsigned short)(v.z & 0xffff)); a[5] += bf2f((unsigned short)(v.z >> 16));
        a[6] += bf2f((unsigned short)(v.w & 0xffff)); a[7] += bf2f((unsigned short)(v.w >> 16));
    }
    float4 e0 = *(const float4*)(enc_w + base);
    float4 e1 = *(const float4*)(enc_w + base + 4);
    a[0] = 0.5f * (a[0] + e0.x); a[1] = 0.5f * (a[1] + e0.y);
    a[2] = 0.5f * (a[2] + e0.z); a[3] = 0.5f * (a[3] + e0.w);
    a[4] = 0.5f * (a[4] + e1.x); a[5] = 0.5f * (a[5] + e1.y);
    a[6] = 0.5f * (a[6] + e1.z); a[7] = 0.5f * (a[7] + e1.w);
    #pragma unroll
    for (int k = 0; k < 4; ++k) {
        float4 c0 = *(const float4*)(catesT + (size_t)k * 8192 + n);
        float4 c1 = *(const float4*)(catesT + (size_t)k * 8192 + n + 4);
        uint4 pk;
        pk.x = pk2bf(a[0] * c0.x, a[1] * c0.y); pk.y = pk2bf(a[2] * c0.z, a[3] * c0.w);
        pk.z = pk2bf(a[4] * c1.x, a[5] * c1.y); pk.w = pk2bf(a[6] * c1.z, a[7] * c1.w);
        *(uint4*)(G + (size_t)(k * 128 + o) * 8192 + n) = pk;
    }
}

// sum 32 bf16 h-partials, scale by inv4, +bias; write mu (f32 + bf16) and logvar
__global__ __launch_bounds__(128) void k_reduce_h2(const unsigned short* __restrict__ hpart,
                                                   const float* __restrict__ enc_b,
                                                   const float* __restrict__ inv4,
                                                   unsigned short* __restrict__ mu_bf,
                                                   float* __restrict__ outp) {
    int r = blockIdx.x;                 // k*512 + b
    int k = r >> 9, b = r & 511;
    int o = threadIdx.x;
    float s = 0.f;
    #pragma unroll
    for (int sp = 0; sp < 32; ++sp)
        s += bf2f(hpart[(size_t)sp * 262144 + (size_t)b * 512 + k * 128 + o]);
    s = s * inv4[b * 4 + k] + enc_b[o];
    const size_t MU0 = (size_t)512 * 8192;
    const size_t LV0 = MU0 + (size_t)2048 * 64;
    if (o < 64) {
        float ss = s * s;
        #pragma unroll
        for (int off = 32; off; off >>= 1) ss += __shfl_xor(ss, off, 64);
        float inv = 1.f / fmaxf(sqrtf(ss), 1e-12f);
        float mv = s * inv;
        outp[MU0 + (size_t)r * 64 + o] = mv;
        mu_bf[(size_t)r * 64 + o] = f2bf(mv);
    } else {
        outp[LV0 + (size_t)r * 64 + (o - 64)] = -s;
    }
}

// MFMA logits: per block 128(b) x 128(n), loop 4 protos; out = log(sum_k exp(z_k . item) * cates_k)
__global__ __launch_bounds__(256) void k_logits_mfma(const unsigned short* __restrict__ mu_bf,
                                                     const unsigned short* __restrict__ items_bf,
                                                     const float* __restrict__ catesT,
                                                     float* __restrict__ out) {
    __shared__ unsigned short lA[128 * 64];
    __shared__ unsigned short lB[128 * 64];
    int tid = threadIdx.x;
    int lane = tid & 63, w = tid >> 6, wr = w >> 1, wc = w & 1;
    int nBase = blockIdx.x * 128, bBase = blockIdx.y * 128;
    int srow = tid >> 3;
    int scg = (tid & 7) ^ (srow & 7);
    char* ldsA_w = (char*)lA + w * 1024;
    char* ldsB_w = (char*)lB + w * 1024;

    #pragma unroll
    for (int it = 0; it < 4; ++it) {
        const unsigned short* gb = items_bf + (size_t)(nBase + it * 32 + srow) * 64 + scg * 8;
        __builtin_amdgcn_global_load_lds(AS1P(gb), AS3P(ldsB_w + it * 4096), 16, 0, 0);
    }

    f32x4 p[4][4] = {};
    for (int k = 0; k < 4; ++k) {
        __syncthreads();
        #pragma unroll
        for (int it = 0; it < 4; ++it) {
            const unsigned short* ga = mu_bf + (size_t)(k * 512 + bBase + it * 32 + srow) * 64 + scg * 8;
            __builtin_amdgcn_global_load_lds(AS1P(ga), AS3P(ldsA_w + it * 4096), 16, 0, 0);
        }
        __syncthreads();
        f32x4 acc[4][4] = {};
        #pragma unroll
        for (int kk = 0; kk < 2; ++kk) {
            short8 af[4], bfr[4];
            #pragma unroll
            for (int i = 0; i < 4; ++i) {
                int rowa = wr * 64 + i * 16 + (lane & 15);
                int slot = kk * 4 + (lane >> 4);
                af[i] = *(const short8*)((const char*)lA + rowa * 128 + ((slot ^ (rowa & 7)) * 16));
                int rowb = wc * 64 + i * 16 + (lane & 15);
                bfr[i] = *(const short8*)((const char*)lB + rowb * 128 + ((slot ^ (rowb & 7)) * 16));
            }
            #pragma unroll
            for (int i = 0; i < 4; ++i)
                #pragma unroll
                for (int j = 0; j < 4; ++j)
                    acc[i][j] = __builtin_amdgcn_mfma_f32_16x16x32_bf16(af[i], bfr[j], acc[i][j], 0, 0, 0);
        }
        #pragma unroll
        for (int j = 0; j < 4; ++j) {
            int col = nBase + wc * 64 + j * 16 + (lane & 15);
            float c = catesT[(size_t)k * 8192 + col];
            #pragma unroll
            for (int i = 0; i < 4; ++i)
                #pragma unroll
                for (int r = 0; r < 4; ++r)
                    p[i][j][r] += __expf(acc[i][j][r]) * c;
        }
    }
    #pragma unroll
    for (int i = 0; i < 4; ++i) {
        int rbase = bBase + wr * 64 + i * 16 + (lane >> 4) * 4;
        #pragma unroll
        for (int j = 0; j < 4; ++j) {
            int col = nBase + wc * 64 + j * 16 + (lane & 15);
            #pragma unroll
            for (int r = 0; r < 4; ++r)
                out[(size_t)(rbase + r) * 8192 + col] = __logf(p[i][j][r]);
        }
    }
}

extern "C" void kernel_launch(void* const* d_in, const int* in_sizes, int n_in,
                              void* d_out, int out_size, void* d_ws, size_t ws_size,
                              hipStream_t stream) {
    const float* rating   = (const float*)d_in[0];   // [512][8192]
    const float* adj      = (const float*)d_in[1];   // [8192][8192]
    const float* item_emb = (const float*)d_in[2];   // [8192][64]
    const float* proto    = (const float*)d_in[3];   // [4][64]
    const float* enc_w    = (const float*)d_in[4];   // [128][8192]
    const float* enc_b    = (const float*)d_in[5];   // [128]
    float* out = (float*)d_out;

    char* ws = (char*)d_ws;
    unsigned short* adj_bf    = (unsigned short*)ws;                      // 128 MiB
    unsigned short* part_bf   = adj_bf + (size_t)8192 * 8192;             // 8*128*8192 bf16 = 16 MiB
    unsigned short* rating_bf = part_bf + (size_t)8 * 1048576;            // 8 MiB
    unsigned short* G         = rating_bf + (size_t)512 * 8192;           // 8 MiB
    unsigned short* W1T       = G + (size_t)512 * 8192;                   // 2 MiB
    unsigned short* encw      = W1T + (size_t)128 * 8192;                 // 2 MiB
    unsigned short* hpart     = encw + (size_t)128 * 8192;                // 32*512*512 bf16 = 16 MiB
    unsigned short* items_bf  = hpart + (size_t)32 * 262144;              // 1 MiB
    unsigned short* mu_bf     = items_bf + (size_t)8192 * 64;             // 0.25 MiB
    float* catesT = (float*)(mu_bf + (size_t)2048 * 64);                  // 4*8192 f32
    float* inv4   = catesT + (size_t)4 * 8192;                            // 2048 f32

    // prep: adj->bf16 nt-read (32768 blk) | enc_w->bf16 (512 blk) | items norm+cates (32 blk)
    k_mega<<<33312, 256, 0, stream>>>(adj, adj_bf, enc_w, encw, item_emb, proto, items_bf, catesT);

    // W1T[o][n] partials = encw @ adj_bf^T  (A=encw 128 rows; split-K 8, dbuf pipeline)
    k_gemm_part<<<dim3(64, 1, 8), 256, 0, stream>>>(encw, adj_bf, part_bf, 128, 1024, 8192, 8192, 8192);
    // reduce->W1T (512 blk, no transpose) | rating cast + inv4 (512 blk)
    k_redW<<<1024, 256, 0, stream>>>(part_bf, W1T, rating, catesT, rating_bf, inv4);

    // W2T partials = W1T @ adj_bf^T ; reduce folds enc_w + cates -> G
    k_gemm_part<<<dim3(64, 1, 8), 256, 0, stream>>>(W1T, adj_bf, part_bf, 128, 1024, 8192, 8192, 8192);
    k_red_G<<<512, 256, 0, stream>>>(part_bf, enc_w, catesT, G);

    // h = rating_bf @ G^T  (split-K 32 -> 512 blocks, 2/CU)
    k_gemm_part<<<dim3(4, 4, 32), 256, 0, stream>>>(rating_bf, G, hpart, 512, 256, 8192, 8192, 512);
    k_reduce_h2<<<2048, 128, 0, stream>>>(hpart, enc_b, inv4, mu_bf, out);

    k_logits_mfma<<<dim3(64, 4), 256, 0, stream>>>(mu_bf, items_bf, catesT, out);
}

// Round 11
// 171.443 us; speedup vs baseline: 1.3050x; 1.0210x over previous
//
#include <hip/hip_runtime.h>

typedef __attribute__((ext_vector_type(8))) short short8;
typedef __attribute__((ext_vector_type(4))) float f32x4;

#define AS3P(x) ((__attribute__((address_space(3))) void*)(x))
#define AS1P(x) ((const __attribute__((address_space(1))) void*)(x))

__device__ __forceinline__ unsigned short f2bf(float f) {
    unsigned int u = __float_as_uint(f);
    u += 0x7fffu + ((u >> 16) & 1u);   // RNE
    return (unsigned short)(u >> 16);
}
__device__ __forceinline__ float bf2f(unsigned short b) {
    return __uint_as_float(((unsigned int)b) << 16);
}
__device__ __forceinline__ unsigned int pk2bf(float a, float b) {
    return (unsigned int)f2bf(a) | ((unsigned int)f2bf(b) << 16);
}
__device__ __forceinline__ float waveReduceSum(float v) {
    #pragma unroll
    for (int off = 32; off; off >>= 1) v += __shfl_xor(v, off, 64);
    return v;
}

// ---------------- mega prep: adj cast (nt reads) | enc_w cast | items prep ----------------
__global__ __launch_bounds__(256) void k_mega(const float* __restrict__ adj,
                                              unsigned short* __restrict__ adj_bf,
                                              const float* __restrict__ enc_w,
                                              unsigned short* __restrict__ encw,
                                              const float* __restrict__ item_emb,
                                              const float* __restrict__ proto,
                                              unsigned short* __restrict__ items_bf,
                                              float* __restrict__ catesT) {
    __shared__ float sp[256];
    int bx = blockIdx.x, tid = threadIdx.x;
    if (bx < 32768) {
        // adj cast: NON-TEMPORAL f32 reads (nt -> no L3 allocation) so adj_bf stays L3-resident
        size_t i = ((size_t)bx * 256 + tid) * 8;
        f32x4 a = __builtin_nontemporal_load((const f32x4*)(adj + i));
        f32x4 b = __builtin_nontemporal_load((const f32x4*)(adj + i + 4));
        uint4 pk;
        pk.x = pk2bf(a[0], a[1]); pk.y = pk2bf(a[2], a[3]);
        pk.z = pk2bf(b[0], b[1]); pk.w = pk2bf(b[2], b[3]);
        *(uint4*)(adj_bf + i) = pk;
        return;
    }
    if (bx < 33280) {
        size_t i = (((size_t)bx - 32768) * 256 + tid) * 8;
        float4 a = *(const float4*)(enc_w + i);
        float4 b = *(const float4*)(enc_w + i + 4);
        uint4 pk;
        pk.x = pk2bf(a.x, a.y); pk.y = pk2bf(a.z, a.w);
        pk.z = pk2bf(b.x, b.y); pk.w = pk2bf(b.z, b.w);
        *(uint4*)(encw + i) = pk;
        return;
    }
    // ---- items prep ----
    sp[tid] = proto[tid];
    __syncthreads();
    {
        float v = sp[tid];
        float ss = waveReduceSum(v * v);   // wave w == proto row w
        sp[tid] = v * (1.f / fmaxf(sqrtf(ss), 1e-12f));
    }
    __syncthreads();
    int i = (bx - 33280) * 256 + tid;
    const float4* row = (const float4*)(item_emb + (size_t)i * 64);
    float4 f[16];
    float ss = 0.f;
    #pragma unroll
    for (int q = 0; q < 16; ++q) {
        f[q] = row[q];
        ss += f[q].x * f[q].x + f[q].y * f[q].y + f[q].z * f[q].z + f[q].w * f[q].w;
    }
    float inv = 1.f / fmaxf(sqrtf(ss), 1e-12f);
    float dots[4] = {0.f, 0.f, 0.f, 0.f};
    unsigned short* ob = items_bf + (size_t)i * 64;
    #pragma unroll
    for (int q = 0; q < 16; ++q) {
        f[q].x *= inv; f[q].y *= inv; f[q].z *= inv; f[q].w *= inv;
        #pragma unroll
        for (int k = 0; k < 4; ++k) {
            dots[k] += f[q].x * sp[k * 64 + q * 4 + 0] + f[q].y * sp[k * 64 + q * 4 + 1]
                     + f[q].z * sp[k * 64 + q * 4 + 2] + f[q].w * sp[k * 64 + q * 4 + 3];
        }
    }
    #pragma unroll
    for (int q = 0; q < 16; q += 2) {
        uint4 pk;
        pk.x = pk2bf(f[q].x, f[q].y);         pk.y = pk2bf(f[q].z, f[q].w);
        pk.z = pk2bf(f[q + 1].x, f[q + 1].y); pk.w = pk2bf(f[q + 1].z, f[q + 1].w);
        *(uint4*)(ob + q * 4) = pk;
    }
    float m = fmaxf(fmaxf(dots[0], dots[1]), fmaxf(dots[2], dots[3]));
    float e0 = expf(dots[0] - m), e1 = expf(dots[1] - m), e2 = expf(dots[2] - m), e3 = expf(dots[3] - m);
    float is = 1.f / (e0 + e1 + e2 + e3);
    catesT[0 * 8192 + i] = e0 * is;
    catesT[1 * 8192 + i] = e1 * is;
    catesT[2 * 8192 + i] = e2 * is;
    catesT[3 * 8192 + i] = e3 * is;
}

// ---------------- MFMA GEMM C = A @ B^T (bf16, K-contig), bf16 split-K partials ----------------
// 2-phase double-buffered: next-tile global_load_lds issued BEFORE current compute.
__global__ __launch_bounds__(256) void k_gemm_part(const unsigned short* __restrict__ A,
                                                   const unsigned short* __restrict__ B,
                                                   unsigned short* __restrict__ Cout,
                                                   int M, int ksplit, int lda, int ldb, int ldc) {
    __shared__ unsigned short lA[2][128 * 64];
    __shared__ unsigned short lB[2][128 * 64];
    int tid = threadIdx.x;
    int lane = tid & 63;
    int w = tid >> 6;
    int wr = w >> 1, wc = w & 1;
    int mBase = blockIdx.y * 128;
    int nBase = blockIdx.x * 128;
    int Kbeg = blockIdx.z * ksplit;
    int Kend = Kbeg + ksplit;

    f32x4 acc[4][4] = {};

    const unsigned short* Ablk = A + (size_t)mBase * lda;
    const unsigned short* Bblk = B + (size_t)nBase * ldb;
    int srow = tid >> 3;
    int scg = (tid & 7) ^ (srow & 7);

    #define STAGE(buf, k0)                                                                     \
        do {                                                                                   \
            char* ldsA_w = (char*)lA[buf] + w * 1024;                                          \
            char* ldsB_w = (char*)lB[buf] + w * 1024;                                          \
            _Pragma("unroll")                                                                  \
            for (int it = 0; it < 4; ++it) {                                                   \
                const unsigned short* ga = Ablk + (size_t)(it * 32 + srow) * lda + (k0) + scg * 8; \
                __builtin_amdgcn_global_load_lds(AS1P(ga), AS3P(ldsA_w + it * 4096), 16, 0, 0);    \
                const unsigned short* gb = Bblk + (size_t)(it * 32 + srow) * ldb + (k0) + scg * 8; \
                __builtin_amdgcn_global_load_lds(AS1P(gb), AS3P(ldsB_w + it * 4096), 16, 0, 0);    \
            }                                                                                  \
        } while (0)

    STAGE(0, Kbeg);
    __syncthreads();
    int cur = 0;
    for (int k0 = Kbeg; k0 < Kend; k0 += 64) {
        if (k0 + 64 < Kend) STAGE(cur ^ 1, k0 + 64);
        #pragma unroll
        for (int kk = 0; kk < 2; ++kk) {
            short8 af[4], bfr[4];
            #pragma unroll
            for (int i = 0; i < 4; ++i) {
                int rowa = wr * 64 + i * 16 + (lane & 15);
                int slot = kk * 4 + (lane >> 4);
                af[i] = *(const short8*)((const char*)lA[cur] + rowa * 128 + ((slot ^ (rowa & 7)) * 16));
                int rowb = wc * 64 + i * 16 + (lane & 15);
                bfr[i] = *(const short8*)((const char*)lB[cur] + rowb * 128 + ((slot ^ (rowb & 7)) * 16));
            }
            #pragma unroll
            for (int i = 0; i < 4; ++i)
                #pragma unroll
                for (int j = 0; j < 4; ++j)
                    acc[i][j] = __builtin_amdgcn_mfma_f32_16x16x32_bf16(af[i], bfr[j], acc[i][j], 0, 0, 0);
        }
        __syncthreads();
        cur ^= 1;
    }
    #undef STAGE

    unsigned short* outP = Cout + (size_t)blockIdx.z * M * ldc;
    #pragma unroll
    for (int i = 0; i < 4; ++i) {
        int rbase = mBase + wr * 64 + i * 16 + (lane >> 4) * 4;
        #pragma unroll
        for (int j = 0; j < 4; ++j) {
            int col = nBase + wc * 64 + j * 16 + (lane & 15);
            #pragma unroll
            for (int r = 0; r < 4; ++r)
                outP[(size_t)(rbase + r) * ldc + col] = f2bf(acc[i][j][r]);
        }
    }
}

// bx<512: sum 8 bf16 partials [sp][128][8192] -> W1T bf16  |  bx>=512: rating cast + inv4
__global__ __launch_bounds__(256) void k_redW(const unsigned short* __restrict__ part,
                                              unsigned short* __restrict__ W1T,
                                              const float* __restrict__ rating,
                                              const float* __restrict__ catesT,
                                              unsigned short* __restrict__ rating_bf,
                                              float* __restrict__ inv4) {
    int tid = threadIdx.x;
    if (blockIdx.x < 512) {
        size_t base = ((size_t)blockIdx.x * 256 + tid) * 8;
        float a[8] = {0.f,0.f,0.f,0.f,0.f,0.f,0.f,0.f};
        #pragma unroll
        for (int sp = 0; sp < 8; ++sp) {
            uint4 v = *(const uint4*)(part + (size_t)sp * 1048576 + base);
            a[0] += bf2f((unsigned short)(v.x & 0xffff)); a[1] += bf2f((unsigned short)(v.x >> 16));
            a[2] += bf2f((unsigned short)(v.y & 0xffff)); a[3] += bf2f((unsigned short)(v.y >> 16));
            a[4] += bf2f((unsigned short)(v.z & 0xffff)); a[5] += bf2f((unsigned short)(v.z >> 16));
            a[6] += bf2f((unsigned short)(v.w & 0xffff)); a[7] += bf2f((unsigned short)(v.w >> 16));
        }
        uint4 pk;
        pk.x = pk2bf(a[0], a[1]); pk.y = pk2bf(a[2], a[3]);
        pk.z = pk2bf(a[4], a[5]); pk.w = pk2bf(a[6], a[7]);
        *(uint4*)(W1T + base) = pk;
        return;
    }
    __shared__ float t[16];
    int b = blockIdx.x - 512;
    const float* row = rating + (size_t)b * 8192;
    float s0 = 0.f, s1 = 0.f, s2 = 0.f, s3 = 0.f;
    #pragma unroll
    for (int j = 0; j < 8; ++j) {
        int i4 = tid + j * 256;
        f32x4 r = __builtin_nontemporal_load((const f32x4*)(row + i4 * 4));
        ushort4 pk;
        pk.x = f2bf(r[0]); pk.y = f2bf(r[1]); pk.z = f2bf(r[2]); pk.w = f2bf(r[3]);
        *(ushort4*)(rating_bf + (size_t)b * 8192 + i4 * 4) = pk;
        float4 c0 = *(const float4*)(catesT + 0 * 8192 + i4 * 4);
        float4 c1 = *(const float4*)(catesT + 1 * 8192 + i4 * 4);
        float4 c2 = *(const float4*)(catesT + 2 * 8192 + i4 * 4);
        float4 c3 = *(const float4*)(catesT + 3 * 8192 + i4 * 4);
        float px, py, pz, pw;
        px = r[0] * c0.x; py = r[1] * c0.y; pz = r[2] * c0.z; pw = r[3] * c0.w;
        s0 += px * px + py * py + pz * pz + pw * pw;
        px = r[0] * c1.x; py = r[1] * c1.y; pz = r[2] * c1.z; pw = r[3] * c1.w;
        s1 += px * px + py * py + pz * pz + pw * pw;
        px = r[0] * c2.x; py = r[1] * c2.y; pz = r[2] * c2.z; pw = r[3] * c2.w;
        s2 += px * px + py * py + pz * pz + pw * pw;
        px = r[0] * c3.x; py = r[1] * c3.y; pz = r[2] * c3.z; pw = r[3] * c3.w;
        s3 += px * px + py * py + pz * pz + pw * pw;
    }
    s0 = waveReduceSum(s0); s1 = waveReduceSum(s1);
    s2 = waveReduceSum(s2); s3 = waveReduceSum(s3);
    if ((tid & 63) == 0) {
        int w = tid >> 6;
        t[w * 4 + 0] = s0; t[w * 4 + 1] = s1; t[w * 4 + 2] = s2; t[w * 4 + 3] = s3;
    }
    __syncthreads();
    if (tid < 4) {
        float ss = t[0 * 4 + tid] + t[1 * 4 + tid] + t[2 * 4 + tid] + t[3 * 4 + tid];
        inv4[b * 4 + tid] = 1.f / fmaxf(sqrtf(ss), 1e-12f);
    }
}

// sum 8 bf16 partials [sp][128][8192] (=W2T), fold enc_w and cates ->
// G[k*128+o][n] = bf16(cates[k][n] * 0.5*(W2T[o][n]+enc_w[o][n]))
__global__ __launch_bounds__(256) void k_red_G(const unsigned short* __restrict__ part,
                                               const float* __restrict__ enc_w,
                                               const float* __restrict__ catesT,
                                               unsigned short* __restrict__ G) {
    size_t base = ((size_t)blockIdx.x * 256 + threadIdx.x) * 8;
    int o = (int)(base >> 13);
    int n = (int)(base & 8191);
    float a[8] = {0.f,0.f,0.f,0.f,0.f,0.f,0.f,0.f};
    #pragma unroll
    for (int sp = 0; sp < 8; ++sp) {
        uint4 v = *(const uint4*)(part + (size_t)sp * 1048576 + base);
        a[0] += bf2f((unsigned short)(v.x & 0xffff)); a[1] += bf2f((unsigned short)(v.x >> 16));
        a[2] += bf2f((unsigned short)(v.y & 0xffff)); a[3] += bf2f((unsigned short)(v.y >> 16));
        a[4] += bf2f((unsigned short)(v.z & 0xffff)); a[5] += bf2f((unsigned short)(v.z >> 16));
        a[6] += bf2f((unsigned short)(v.w & 0xffff)); a[7] += bf2f((unsigned short)(v.w >> 16));
    }
    float4 e0 = *(const float4*)(enc_w + base);
    float4 e1 = *(const float4*)(enc_w + base + 4);
    a[0] = 0.5f * (a[0] + e0.x); a[1] = 0.5f * (a[1] + e0.y);
    a[2] = 0.5f * (a[2] + e0.z); a[3] = 0.5f * (a[3] + e0.w);
    a[4] = 0.5f * (a[4] + e1.x); a[5] = 0.5f * (a[5] + e1.y);
    a[6] = 0.5f * (a[6] + e1.z); a[7] = 0.5f * (a[7] + e1.w);
    #pragma unroll
    for (int k = 0; k < 4; ++k) {
        float4 c0 = *(const float4*)(catesT + (size_t)k * 8192 + n);
        float4 c1 = *(const float4*)(catesT + (size_t)k * 8192 + n + 4);
        uint4 pk;
        pk.x = pk2bf(a[0] * c0.x, a[1] * c0.y); pk.y = pk2bf(a[2] * c0.z, a[3] * c0.w);
        pk.z = pk2bf(a[4] * c1.x, a[5] * c1.y); pk.w = pk2bf(a[6] * c1.z, a[7] * c1.w);
        *(uint4*)(G + (size_t)(k * 128 + o) * 8192 + n) = pk;
    }
}

// sum 16 bf16 h-partials, scale by inv4, +bias; write mu (f32 + bf16) and logvar
__global__ __launch_bounds__(128) void k_reduce_h2(const unsigned short* __restrict__ hpart,
                                                   const float* __restrict__ enc_b,
                                                   const float* __restrict__ inv4,
                                                   unsigned short* __restrict__ mu_bf,
                                                   float* __restrict__ outp) {
    int r = blockIdx.x;                 // k*512 + b
    int k = r >> 9, b = r & 511;
    int o = threadIdx.x;
    float s = 0.f;
    #pragma unroll
    for (int sp = 0; sp < 16; ++sp)
        s += bf2f(hpart[(size_t)sp * 262144 + (size_t)b * 512 + k * 128 + o]);
    s = s * inv4[b * 4 + k] + enc_b[o];
    const size_t MU0 = (size_t)512 * 8192;
    const size_t LV0 = MU0 + (size_t)2048 * 64;
    if (o < 64) {
        float ss = s * s;
        #pragma unroll
        for (int off = 32; off; off >>= 1) ss += __shfl_xor(ss, off, 64);
        float inv = 1.f / fmaxf(sqrtf(ss), 1e-12f);
        float mv = s * inv;
        outp[MU0 + (size_t)r * 64 + o] = mv;
        mu_bf[(size_t)r * 64 + o] = f2bf(mv);
    } else {
        outp[LV0 + (size_t)r * 64 + (o - 64)] = -s;
    }
}

// MFMA logits: per block 128(b) x 128(n); single-stage LDS (items + all 4 mu slabs), one barrier
__global__ __launch_bounds__(256) void k_logits_mfma(const unsigned short* __restrict__ mu_bf,
                                                     const unsigned short* __restrict__ items_bf,
                                                     const float* __restrict__ catesT,
                                                     float* __restrict__ out) {
    __shared__ unsigned short lA[4][128 * 64];   // 64 KiB: mu for 4 protos
    __shared__ unsigned short lB[128 * 64];      // 16 KiB: items
    int tid = threadIdx.x;
    int lane = tid & 63, w = tid >> 6, wr = w >> 1, wc = w & 1;
    int nBase = blockIdx.x * 128, bBase = blockIdx.y * 128;
    int srow = tid >> 3;
    int scg = (tid & 7) ^ (srow & 7);
    char* ldsB_w = (char*)lB + w * 1024;

    #pragma unroll
    for (int it = 0; it < 4; ++it) {
        const unsigned short* gb = items_bf + (size_t)(nBase + it * 32 + srow) * 64 + scg * 8;
        __builtin_amdgcn_global_load_lds(AS1P(gb), AS3P(ldsB_w + it * 4096), 16, 0, 0);
    }
    #pragma unroll
    for (int k = 0; k < 4; ++k) {
        char* ldsA_w = (char*)lA[k] + w * 1024;
        #pragma unroll
        for (int it = 0; it < 4; ++it) {
            const unsigned short* ga = mu_bf + (size_t)(k * 512 + bBase + it * 32 + srow) * 64 + scg * 8;
            __builtin_amdgcn_global_load_lds(AS1P(ga), AS3P(ldsA_w + it * 4096), 16, 0, 0);
        }
    }
    __syncthreads();

    f32x4 p[4][4] = {};
    #pragma unroll
    for (int k = 0; k < 4; ++k) {
        f32x4 acc[4][4] = {};
        #pragma unroll
        for (int kk = 0; kk < 2; ++kk) {
            short8 af[4], bfr[4];
            #pragma unroll
            for (int i = 0; i < 4; ++i) {
                int rowa = wr * 64 + i * 16 + (lane & 15);
                int slot = kk * 4 + (lane >> 4);
                af[i] = *(const short8*)((const char*)lA[k] + rowa * 128 + ((slot ^ (rowa & 7)) * 16));
                int rowb = wc * 64 + i * 16 + (lane & 15);
                bfr[i] = *(const short8*)((const char*)lB + rowb * 128 + ((slot ^ (rowb & 7)) * 16));
            }
            #pragma unroll
            for (int i = 0; i < 4; ++i)
                #pragma unroll
                for (int j = 0; j < 4; ++j)
                    acc[i][j] = __builtin_amdgcn_mfma_f32_16x16x32_bf16(af[i], bfr[j], acc[i][j], 0, 0, 0);
        }
        #pragma unroll
        for (int j = 0; j < 4; ++j) {
            int col = nBase + wc * 64 + j * 16 + (lane & 15);
            float c = catesT[(size_t)k * 8192 + col];
            #pragma unroll
            for (int i = 0; i < 4; ++i)
                #pragma unroll
                for (int r = 0; r < 4; ++r)
                    p[i][j][r] += __expf(acc[i][j][r]) * c;
        }
    }
    #pragma unroll
    for (int i = 0; i < 4; ++i) {
        int rbase = bBase + wr * 64 + i * 16 + (lane >> 4) * 4;
        #pragma unroll
        for (int j = 0; j < 4; ++j) {
            int col = nBase + wc * 64 + j * 16 + (lane & 15);
            #pragma unroll
            for (int r = 0; r < 4; ++r)
                out[(size_t)(rbase + r) * 8192 + col] = __logf(p[i][j][r]);
        }
    }
}

extern "C" void kernel_launch(void* const* d_in, const int* in_sizes, int n_in,
                              void* d_out, int out_size, void* d_ws, size_t ws_size,
                              hipStream_t stream) {
    const float* rating   = (const float*)d_in[0];   // [512][8192]
    const float* adj      = (const float*)d_in[1];   // [8192][8192]
    const float* item_emb = (const float*)d_in[2];   // [8192][64]
    const float* proto    = (const float*)d_in[3];   // [4][64]
    const float* enc_w    = (const float*)d_in[4];   // [128][8192]
    const float* enc_b    = (const float*)d_in[5];   // [128]
    float* out = (float*)d_out;

    char* ws = (char*)d_ws;
    unsigned short* adj_bf    = (unsigned short*)ws;                      // 128 MiB
    unsigned short* part_bf   = adj_bf + (size_t)8192 * 8192;             // 8*128*8192 bf16 = 16 MiB
    unsigned short* rating_bf = part_bf + (size_t)8 * 1048576;            // 8 MiB
    unsigned short* G         = rating_bf + (size_t)512 * 8192;           // 8 MiB
    unsigned short* W1T       = G + (size_t)512 * 8192;                   // 2 MiB
    unsigned short* encw      = W1T + (size_t)128 * 8192;                 // 2 MiB
    unsigned short* hpart     = encw + (size_t)128 * 8192;                // 16*512*512 bf16 = 8 MiB
    unsigned short* items_bf  = hpart + (size_t)16 * 262144;              // 1 MiB
    unsigned short* mu_bf     = items_bf + (size_t)8192 * 64;             // 0.25 MiB
    float* catesT = (float*)(mu_bf + (size_t)2048 * 64);                  // 4*8192 f32
    float* inv4   = catesT + (size_t)4 * 8192;                            // 2048 f32

    // prep: adj->bf16 nt-read (32768 blk) | enc_w->bf16 (512 blk) | items norm+cates (32 blk)
    k_mega<<<33312, 256, 0, stream>>>(adj, adj_bf, enc_w, encw, item_emb, proto, items_bf, catesT);

    // W1T[o][n] partials = encw @ adj_bf^T  (A=encw 128 rows; split-K 8, dbuf pipeline)
    k_gemm_part<<<dim3(64, 1, 8), 256, 0, stream>>>(encw, adj_bf, part_bf, 128, 1024, 8192, 8192, 8192);
    // reduce->W1T (512 blk, no transpose) | rating cast + inv4 (512 blk)
    k_redW<<<1024, 256, 0, stream>>>(part_bf, W1T, rating, catesT, rating_bf, inv4);

    // W2T partials = W1T @ adj_bf^T ; reduce folds enc_w + cates -> G
    k_gemm_part<<<dim3(64, 1, 8), 256, 0, stream>>>(W1T, adj_bf, part_bf, 128, 1024, 8192, 8192, 8192);
    k_red_G<<<512, 256, 0, stream>>>(part_bf, enc_w, catesT, G);

    // h = rating_bf @ G^T  (split-K 16 -> 256 blocks; dbuf pipeline)
    k_gemm_part<<<dim3(4, 4, 16), 256, 0, stream>>>(rating_bf, G, hpart, 512, 512, 8192, 8192, 512);
    k_reduce_h2<<<2048, 128, 0, stream>>>(hpart, enc_b, inv4, mu_bf, out);

    k_logits_mfma<<<dim3(64, 4), 256, 0, stream>>>(mu_bf, items_bf, catesT, out);
}